// Round 1
// 519.818 us; speedup vs baseline: 1.0543x; 1.0543x over previous
//
#include <hip/hip_runtime.h>
#include <hip/hip_bf16.h>

#define NN 50000
#define EE 400000
#define EP 450000   // EE + NN self-loops

typedef __attribute__((ext_vector_type(8))) short short8;
typedef __attribute__((ext_vector_type(4))) float f32x4;

__device__ __forceinline__ float bf2f(__hip_bfloat16 b) { return __bfloat162float(b); }
__device__ __forceinline__ float us2f(unsigned short u) {
    unsigned int x = ((unsigned int)u) << 16;
    union { unsigned int i; float f; } c; c.i = x; return c.f;
}
__device__ __forceinline__ unsigned short f2bfu(float f) {   // f32 -> bf16 bits, RNE
    union { float f; unsigned int u; } c; c.f = f;
    unsigned int r = c.u + 0x7FFFu + ((c.u >> 16) & 1u);
    return (unsigned short)(r >> 16);
}

// Fragment loaders: 8 contiguous K-elements -> short8 of bf16 bits.
__device__ __forceinline__ short8 load_frag(const __hip_bfloat16* p) {
    return *(const short8*)p;
}
__device__ __forceinline__ short8 load_frag(const float* p) {
    const float4* q = (const float4*)p;
    float4 a = q[0], b = q[1];
    short8 r;
    r[0] = (short)f2bfu(a.x); r[1] = (short)f2bfu(a.y);
    r[2] = (short)f2bfu(a.z); r[3] = (short)f2bfu(a.w);
    r[4] = (short)f2bfu(b.x); r[5] = (short)f2bfu(b.y);
    r[6] = (short)f2bfu(b.z); r[7] = (short)f2bfu(b.w);
    return r;
}

// ---------------------------------------------------------------------------
// Weight pre-convert: W1 and W2 f32 -> bf16, one kernel.
// ---------------------------------------------------------------------------
__global__ void cvt2_kernel(const float* __restrict__ W1, const float* __restrict__ W2,
                            __hip_bfloat16* __restrict__ w1b, __hip_bfloat16* __restrict__ w2b) {
    int i = blockIdx.x * blockDim.x + threadIdx.x;
    if (i < 65536) w1b[i] = __float2bfloat16(W1[i]);
    else if (i < 131072) w2b[i - 65536] = __float2bfloat16(W2[i - 65536]);
}

// ---------------------------------------------------------------------------
// usd[row][k], row 0..3 = u_s per head, 4..7 = u_d per head (f32, exact):
//   u_s[h][k] = sum_c a1s[h][c] * W1[h*128+c][k]
// Lets layer-1 attention logits be computed as s1[n,h] = x[n] . u_s[h]
// without materializing h1 = x @ W1^T.
// ---------------------------------------------------------------------------
__global__ void usd_kernel(const float* __restrict__ W1,
                           const float* __restrict__ a1s, const float* __restrict__ a1d,
                           float* __restrict__ usd) {
    int t = blockIdx.x * blockDim.x + threadIdx.x;
    if (t >= 1024) return;
    int row = t >> 7, k = t & 127;
    int hh = row & 3;
    const float* av = (row < 4) ? (a1s + hh * 128) : (a1d + hh * 128);
    const float* wp = W1 + (size_t)(hh * 128) * 128 + k;
    float acc = 0.f;
    for (int c = 0; c < 128; c++) acc += av[c] * wp[(size_t)c * 128];
    usd[t] = acc;
}

// ---------------------------------------------------------------------------
// Fused: x (f32) -> xb (bf16) convert + s1/d1 = x . usd (f32 dots, butterfly
// reduce over the 4 quads). One wave owns 16 rows, lane (r,quad) holds 32 cols.
// ---------------------------------------------------------------------------
__global__ void cvtx_sd(const float* __restrict__ x, const float* __restrict__ usd,
                        __hip_bfloat16* __restrict__ xb,
                        float* __restrict__ s, float* __restrict__ d, int M) {
    __shared__ float us_s[1024];
    for (int i = threadIdx.x; i < 1024; i += 256) us_s[i] = usd[i];
    __syncthreads();
    int wave = threadIdx.x >> 6, lane = threadIdx.x & 63;
    int m0 = blockIdx.x * 64 + wave * 16;
    int r = lane & 15, quad = lane >> 4;
    int am = m0 + r; if (am >= M) am = M - 1;
    const float* xp = x + (size_t)am * 128 + quad * 8;
    float xv[32];
#pragma unroll
    for (int kk = 0; kk < 4; kk++) {
        float4 a = *(const float4*)(xp + kk * 32);
        float4 bq = *(const float4*)(xp + kk * 32 + 4);
        xv[kk*8+0]=a.x;  xv[kk*8+1]=a.y;  xv[kk*8+2]=a.z;  xv[kk*8+3]=a.w;
        xv[kk*8+4]=bq.x; xv[kk*8+5]=bq.y; xv[kk*8+6]=bq.z; xv[kk*8+7]=bq.w;
        short8 o;
        o[0]=(short)f2bfu(a.x);  o[1]=(short)f2bfu(a.y);
        o[2]=(short)f2bfu(a.z);  o[3]=(short)f2bfu(a.w);
        o[4]=(short)f2bfu(bq.x); o[5]=(short)f2bfu(bq.y);
        o[6]=(short)f2bfu(bq.z); o[7]=(short)f2bfu(bq.w);
        *(short8*)(xb + (size_t)am * 128 + quad * 8 + kk * 32) = o;
    }
    float acc[8];
#pragma unroll
    for (int o = 0; o < 8; o++) {
        const float* up = us_s + o * 128 + quad * 8;
        float a = 0.f;
#pragma unroll
        for (int kk = 0; kk < 4; kk++)
#pragma unroll
            for (int j = 0; j < 8; j++) a += xv[kk*8+j] * up[kk*32+j];
        acc[o] = a;
    }
#pragma unroll
    for (int o = 0; o < 8; o++) {
        acc[o] += __shfl_xor(acc[o], 16, 64);
        acc[o] += __shfl_xor(acc[o], 32, 64);
    }
    int m = m0 + r;
    if (quad == 0 && m < M) {
#pragma unroll
        for (int hh = 0; hh < 4; hh++) { s[m*4+hh] = acc[hh]; d[m*4+hh] = acc[4+hh]; }
    }
}

// ---------------------------------------------------------------------------
// Layer-1 gather on RAW x (256B rows instead of 1KB h-rows).
// 16 lanes/node, each lane 8 x-channels, 4 head accumulators sharing the read.
// Writes NORMALIZED weighted sums aggn[n, hh*128+c] (bf16).
// ---------------------------------------------------------------------------
__global__ void gather_agg(const int* __restrict__ elist, const int* __restrict__ offsets,
                           const __hip_bfloat16* __restrict__ xb,
                           const float* __restrict__ s, const float* __restrict__ d,
                           __hip_bfloat16* __restrict__ aggn) {
    int gid = blockIdx.x * blockDim.x + threadIdx.x;
    if (gid >= NN * 16) return;
    int node = gid >> 4, t = gid & 15;
    int c0 = t * 8;
    int j0 = offsets[node], j1 = offsets[node + 1];
    float4 dv = *(const float4*)(d + node * 4);
    float den0=0.f, den1=0.f, den2=0.f, den3=0.f;
    float acc0[8], acc1[8], acc2[8], acc3[8];
#pragma unroll
    for (int c = 0; c < 8; c++) { acc0[c]=0.f; acc1[c]=0.f; acc2[c]=0.f; acc3[c]=0.f; }
    const unsigned short* hb = (const unsigned short*)xb;
    for (int j = j0; j < j1; j++) {
        int src = elist[j];
        float4 sv = *(const float4*)(s + src * 4);
        float e0 = sv.x + dv.x; e0 = e0 > 0.f ? e0 : 0.2f * e0; float w0 = __expf(e0); den0 += w0;
        float e1 = sv.y + dv.y; e1 = e1 > 0.f ? e1 : 0.2f * e1; float w1 = __expf(e1); den1 += w1;
        float e2 = sv.z + dv.z; e2 = e2 > 0.f ? e2 : 0.2f * e2; float w2 = __expf(e2); den2 += w2;
        float e3 = sv.w + dv.w; e3 = e3 > 0.f ? e3 : 0.2f * e3; float w3 = __expf(e3); den3 += w3;
        short8 xv = *(const short8*)(hb + (size_t)src * 128 + c0);
#pragma unroll
        for (int c = 0; c < 8; c++) {
            float xf = us2f((unsigned short)xv[c]);
            acc0[c] += w0 * xf; acc1[c] += w1 * xf;
            acc2[c] += w2 * xf; acc3[c] += w3 * xf;
        }
    }
    float i0 = 1.f/den0, i1 = 1.f/den1, i2 = 1.f/den2, i3 = 1.f/den3;
    __hip_bfloat16* op = aggn + (size_t)node * 512 + c0;
    short8 o0, o1, o2, o3;
#pragma unroll
    for (int c = 0; c < 8; c++) {
        o0[c] = (short)f2bfu(acc0[c]*i0); o1[c] = (short)f2bfu(acc1[c]*i1);
        o2[c] = (short)f2bfu(acc2[c]*i2); o3[c] = (short)f2bfu(acc3[c]*i3);
    }
    *(short8*)(op)       = o0;
    *(short8*)(op + 128) = o1;
    *(short8*)(op + 256) = o2;
    *(short8*)(op + 384) = o3;
}

// ---------------------------------------------------------------------------
// Block-diagonal GEMM for layer-1 output:
//   act[n, hh*128+oc] = ELU( sum_c aggn[n,hh,c] * W1[hh*128+oc, c] + b1 )
// A-stationary like gemm_rows; per n-tile only the owning head's 4 k-tiles.
// ---------------------------------------------------------------------------
__global__ void gemm_bdiag(const __hip_bfloat16* __restrict__ A,
                           const __hip_bfloat16* __restrict__ Wb,
                           const float* __restrict__ b,
                           __hip_bfloat16* __restrict__ act, int M) {
    int wave = threadIdx.x >> 6, lane = threadIdx.x & 63;
    int m0 = blockIdx.x * 64 + wave * 16;
    int r = lane & 15, quad = lane >> 4;
    int am = m0 + r; if (am >= M) am = M - 1;
    short8 afrag[16];
    const __hip_bfloat16* arow = A + (size_t)am * 512 + quad * 8;
#pragma unroll
    for (int kk = 0; kk < 16; kk++) afrag[kk] = *(const short8*)(arow + kk * 32);
    const __hip_bfloat16* wrow = Wb + (size_t)r * 128 + quad * 8;
#pragma unroll
    for (int hh = 0; hh < 4; hh++) {
        for (int nb = 0; nb < 128; nb += 16) {
            int n0 = hh * 128 + nb;
            f32x4 acc = {0.f, 0.f, 0.f, 0.f};
#pragma unroll
            for (int kk2 = 0; kk2 < 4; kk2++) {
                short8 bfr = *(const short8*)(wrow + (size_t)n0 * 128 + kk2 * 32);
                acc = __builtin_amdgcn_mfma_f32_16x16x32_bf16(afrag[hh*4+kk2], bfr, acc, 0, 0, 0);
            }
            float bias = b[n0 + r];
#pragma unroll
            for (int i = 0; i < 4; i++) {
                int m = m0 + quad * 4 + i;
                if (m < M) {
                    float v = acc[i] + bias;
                    v = v > 0.f ? v : (__expf(v) - 1.0f);
                    act[(size_t)m * 512 + n0 + r] = __float2bfloat16(v);
                }
            }
        }
    }
}

// ---------------------------------------------------------------------------
// A-stationary GEMM + fused attention-coefficient epilogue (layer 2).
// ---------------------------------------------------------------------------
template<int K, int H, int C, typename TA>
__global__ void gemm_rows(const TA* __restrict__ A,
                          const __hip_bfloat16* __restrict__ Wb,
                          const float* __restrict__ as_, const float* __restrict__ ad_,
                          __hip_bfloat16* __restrict__ Cb,
                          float* __restrict__ s, float* __restrict__ d,
                          int M) {
    constexpr int NO = H * C;
    int wave = threadIdx.x >> 6;
    int lane = threadIdx.x & 63;
    int m0 = blockIdx.x * 64 + wave * 16;
    int r = lane & 15, quad = lane >> 4;
    int am = m0 + r; if (am >= M) am = M - 1;
    constexpr int NK = K / 32;
    short8 afrag[NK];
    const TA* arow = A + (size_t)am * K + quad * 8;
#pragma unroll
    for (int kk = 0; kk < NK; kk++) afrag[kk] = load_frag(arow + kk * 32);
    const __hip_bfloat16* wrow = Wb + (size_t)r * K + quad * 8;
    float sacc[4] = {0.f, 0.f, 0.f, 0.f};
    float dacc[4] = {0.f, 0.f, 0.f, 0.f};
    for (int n0 = 0; n0 < NO; n0 += 16) {
        f32x4 acc = {0.f, 0.f, 0.f, 0.f};
#pragma unroll
        for (int kk = 0; kk < NK; kk++) {
            short8 b = *(const short8*)(wrow + (size_t)n0 * K + kk * 32);
            acc = __builtin_amdgcn_mfma_f32_16x16x32_bf16(afrag[kk], b, acc, 0, 0, 0);
        }
        float as_v = as_[n0 + r];
        float ad_v = ad_[n0 + r];
        // C/D layout: col = lane&15 (n), row = quad*4 + i (m)
#pragma unroll
        for (int i = 0; i < 4; i++) {
            int m = m0 + quad * 4 + i;
            if (m < M) Cb[(size_t)m * NO + n0 + r] = __float2bfloat16(acc[i]);
            sacc[i] += acc[i] * as_v;
            dacc[i] += acc[i] * ad_v;
        }
        if ((n0 & (C - 16)) == C - 16) {      // head boundary: reduce over 16 r-lanes
            int hh = n0 / C;
#pragma unroll
            for (int mask = 1; mask <= 8; mask <<= 1) {
#pragma unroll
                for (int i = 0; i < 4; i++) {
                    sacc[i] += __shfl_xor(sacc[i], mask, 64);
                    dacc[i] += __shfl_xor(dacc[i], mask, 64);
                }
            }
            if (r == 0) {
#pragma unroll
                for (int i = 0; i < 4; i++) {
                    int m = m0 + quad * 4 + i;
                    if (m < M) { s[m * H + hh] = sacc[i]; d[m * H + hh] = dacc[i]; }
                }
            }
#pragma unroll
            for (int i = 0; i < 4; i++) { sacc[i] = 0.f; dacc[i] = 0.f; }
        }
    }
}

// ---------------------------------------------------------------------------
// Tiny GEMM for layer 3 + fused s/d. Split-K: 8 lanes per node, lane t owns
// k-slice [t*16, t*16+16) for ALL 8 outputs; coalesced vector loads;
// butterfly reduce over the 8 lanes.
// ---------------------------------------------------------------------------
__global__ void gemm8_kernel(const __hip_bfloat16* __restrict__ A,
                             const float* __restrict__ W,
                             const float* __restrict__ a3s, const float* __restrict__ a3d,
                             __hip_bfloat16* __restrict__ Cb,
                             float* __restrict__ s, float* __restrict__ d) {
    int gid = blockIdx.x * blockDim.x + threadIdx.x;
    if (gid >= NN * 8) return;
    int n = gid >> 3, t = gid & 7;
    const unsigned short* ap = (const unsigned short*)A + (size_t)n * 128 + t * 16;
    short8 v0 = *(const short8*)ap;
    short8 v1 = *(const short8*)(ap + 8);
    float xf[16];
#pragma unroll
    for (int j = 0; j < 8; j++) { xf[j] = us2f((unsigned short)v0[j]); xf[8+j] = us2f((unsigned short)v1[j]); }
    float acc[8];
#pragma unroll
    for (int c = 0; c < 8; c++) {
        const float* wp = W + c * 128 + t * 16;
        float a = 0.f;
#pragma unroll
        for (int j = 0; j < 16; j++) a += xf[j] * wp[j];
        acc[c] = a;
    }
#pragma unroll
    for (int mask = 1; mask <= 4; mask <<= 1)
#pragma unroll
        for (int c = 0; c < 8; c++) acc[c] += __shfl_xor(acc[c], mask, 64);
    // every lane now holds all 8 dots
    Cb[n * 8 + t] = __float2bfloat16(acc[t]);
    if (t == 0) {
        float sv = 0.f, dvv = 0.f;
#pragma unroll
        for (int c = 0; c < 8; c++) { sv += acc[c] * a3s[c]; dvv += acc[c] * a3d[c]; }
        s[n] = sv; d[n] = dvv;
    }
}

// ---------------------------------------------------------------------------
// CSR build: deg histogram -> single-block scan -> fill (dst-sorted src list)
// ---------------------------------------------------------------------------
__global__ void deg_kernel(const int* __restrict__ ei, int* __restrict__ deg) {
    int e = blockIdx.x * blockDim.x + threadIdx.x;
    if (e >= EP) return;
    int dst = (e < EE) ? ei[EE + e] : e - EE;
    atomicAdd(&deg[dst], 1);
}

#define SCAN_T 1024
__global__ void scan_kernel(const int* __restrict__ deg, int* __restrict__ offsets) {
    __shared__ int part[SCAN_T];
    int t = threadIdx.x;
    constexpr int CHUNK = (NN + SCAN_T - 1) / SCAN_T;   // 49
    int lo = t * CHUNK;
    int hi = lo + CHUNK; if (hi > NN) hi = NN;
    int s = 0;
    for (int i = lo; i < hi && i < NN; i++) s += deg[i];
    part[t] = s;
    __syncthreads();
    for (int off = 1; off < SCAN_T; off <<= 1) {
        int v = (t >= off) ? part[t - off] : 0;
        __syncthreads();
        part[t] += v;
        __syncthreads();
    }
    int run = (t == 0) ? 0 : part[t - 1];
    for (int i = lo; i < hi && i < NN; i++) { offsets[i] = run; run += deg[i]; }
    if (t == SCAN_T - 1) offsets[NN] = run;
}

__global__ void fill_kernel(const int* __restrict__ ei, const int* __restrict__ offsets,
                            int* __restrict__ cursor, int* __restrict__ elist) {
    int e = blockIdx.x * blockDim.x + threadIdx.x;
    if (e >= EP) return;
    int src, dst;
    if (e < EE) { src = ei[e]; dst = ei[EE + e]; } else { src = dst = e - EE; }
    int pos = atomicAdd(&cursor[dst], 1);
    elist[offsets[dst] + pos] = src;
}

// ---------------------------------------------------------------------------
// Fused gather (layers 2,3): w_e = exp(leaky_relu(s[src]+d[node])) inline;
// out[n,c] = (sum_e w_e * h[src_e,c]) / (sum_e w_e); + bias, ELU -> bf16.
// ---------------------------------------------------------------------------
template<int H, int C, int CPL>
__global__ void gather_fused(const int* __restrict__ elist,
                             const int* __restrict__ offsets,
                             const __hip_bfloat16* __restrict__ h,
                             const float* __restrict__ s, const float* __restrict__ d,
                             const float* __restrict__ b,
                             __hip_bfloat16* __restrict__ act) {
    constexpr int HC = H * C;
    constexpr int TPN = HC / CPL;
    int gid = blockIdx.x * blockDim.x + threadIdx.x;
    if (gid >= NN * TPN) return;
    int node = gid / TPN;
    int t = gid - node * TPN;
    int c0 = t * CPL;
    int hh = c0 / C;
    int j0 = offsets[node], j1 = offsets[node + 1];
    float dv = d[node * H + hh];
    float den = 0.f;
    float acc[CPL];
#pragma unroll
    for (int c = 0; c < CPL; c++) acc[c] = 0.f;
    const unsigned short* hb = (const unsigned short*)h;
    for (int j = j0; j < j1; j++) {
        int src = elist[j];
        float x = s[src * H + hh] + dv;
        x = x > 0.f ? x : 0.2f * x;
        float w = __expf(x);
        den += w;
        const unsigned short* hp = hb + (size_t)src * HC + c0;
        if constexpr (CPL == 8) {
            short8 a8 = *(const short8*)hp;
#pragma unroll
            for (int c = 0; c < 8; c++) acc[c] += w * us2f((unsigned short)a8[c]);
        } else {
            ushort2 a = *(const ushort2*)hp;
            acc[0] += w * us2f(a.x);
            acc[1] += w * us2f(a.y);
        }
    }
    float inv = 1.0f / den;   // deg >= 1 (self-loop), den > 0
    __hip_bfloat16* op = act + (size_t)node * HC + c0;
#pragma unroll
    for (int c = 0; c < CPL; c++) {
        float v = acc[c] * inv + b[c0 + c];
        v = v > 0.f ? v : (__expf(v) - 1.0f);
        op[c] = __float2bfloat16(v);
    }
}

// ---------------------------------------------------------------------------
// Final edge MLP: z[19] = [h3[src], h3[dst], ea, yr, qt] -> fc1(relu) -> fc2
// ---------------------------------------------------------------------------
__global__ void mlp_kernel(const int* __restrict__ ei,
                           const __hip_bfloat16* __restrict__ act3,
                           const float* __restrict__ ea,
                           const float* __restrict__ yr,
                           const float* __restrict__ qt,
                           const float* __restrict__ fc1w,
                           const float* __restrict__ fc1b,
                           const float* __restrict__ fc2w,
                           const float* __restrict__ fc2b,
                           float* __restrict__ outp) {
    __shared__ float w1[16 * 19], b1s[16], w2[16];
    for (int i = threadIdx.x; i < 16 * 19; i += blockDim.x) w1[i] = fc1w[i];
    if (threadIdx.x < 16) {
        b1s[threadIdx.x] = fc1b[threadIdx.x];
        w2[threadIdx.x] = fc2w[threadIdx.x];
    }
    __syncthreads();
    int e = blockIdx.x * blockDim.x + threadIdx.x;
    if (e >= EE) return;
    int src = ei[e], dst = ei[EE + e];
    float z[19];
#pragma unroll
    for (int i = 0; i < 8; i++) z[i] = bf2f(act3[src * 8 + i]);
#pragma unroll
    for (int i = 0; i < 8; i++) z[8 + i] = bf2f(act3[dst * 8 + i]);
    z[16] = ea[e]; z[17] = yr[e]; z[18] = qt[e];
    float acc2 = fc2b[0];
#pragma unroll
    for (int j = 0; j < 16; j++) {
        float a = b1s[j];
#pragma unroll
        for (int i = 0; i < 19; i++) a += z[i] * w1[j * 19 + i];
        a = a > 0.f ? a : 0.f;
        acc2 += a * w2[j];
    }
    outp[e] = acc2;
}

// ---------------------------------------------------------------------------
extern "C" void kernel_launch(void* const* d_in, const int* in_sizes, int n_in,
                              void* d_out, int out_size, void* d_ws, size_t ws_size,
                              hipStream_t stream) {
    const float* x    = (const float*)d_in[0];
    const int*   ei   = (const int*)d_in[1];
    const float* ea   = (const float*)d_in[2];
    const float* yr   = (const float*)d_in[3];
    const float* qt   = (const float*)d_in[4];
    const float* W1   = (const float*)d_in[5];
    const float* a1s  = (const float*)d_in[6];
    const float* a1d  = (const float*)d_in[7];
    const float* b1   = (const float*)d_in[8];
    const float* W2   = (const float*)d_in[9];
    const float* a2s  = (const float*)d_in[10];
    const float* a2d  = (const float*)d_in[11];
    const float* b2   = (const float*)d_in[12];
    const float* W3   = (const float*)d_in[13];
    const float* a3s  = (const float*)d_in[14];
    const float* a3d  = (const float*)d_in[15];
    const float* b3   = (const float*)d_in[16];
    const float* fc1w = (const float*)d_in[17];
    const float* fc1b = (const float*)d_in[18];
    const float* fc2w = (const float*)d_in[19];
    const float* fc2b = (const float*)d_in[20];
    float* outp = (float*)d_out;

    char* ws = (char*)d_ws;
    __hip_bfloat16* h_buf   = (__hip_bfloat16*)(ws);                 // N*512 bf16 (51.2 MB): aggn / h2 / h3
    __hip_bfloat16* act_buf = (__hip_bfloat16*)(ws + 51200000);      // N*512 bf16 (51.2 MB): xb / act1 / act2 / act3
    float* s_buf   = (float*)(ws + 102400000);                       // N*4 f32
    float* d_buf   = (float*)(ws + 103200000);                       // N*4 f32
    int*   deg     = (int*)  (ws + 104000000);                       // N ints
    int*   cursor  = (int*)  (ws + 104200000);                       // N ints (contiguous w/ deg)
    int*   offsets = (int*)  (ws + 104400000);                       // N+1 ints
    int*   elist   = (int*)  (ws + 104600016);                       // EP ints (1.8 MB)
    __hip_bfloat16* w1bf = (__hip_bfloat16*)(ws + 106400016);        // 512*128 bf16
    __hip_bfloat16* w2bf = (__hip_bfloat16*)(ws + 106531088);        // 128*512 bf16
    float* usd = (float*)(ws + 106662160);                           // 8*128 f32 (4 KB)
    __hip_bfloat16* xb = act_buf;                                    // N*128 bf16, dead after gather_agg

    // ---- CSR build + weight pre-convert + u-vector precompute ----
    hipMemsetAsync(deg, 0, 2 * NN * sizeof(int), stream);            // deg + cursor
    deg_kernel<<<(EP + 255) / 256, 256, 0, stream>>>(ei, deg);
    cvt2_kernel<<<(131072 + 255) / 256, 256, 0, stream>>>(W1, W2, w1bf, w2bf);
    usd_kernel<<<4, 256, 0, stream>>>(W1, a1s, a1d, usd);
    scan_kernel<<<1, SCAN_T, 0, stream>>>(deg, offsets);
    cvtx_sd<<<(NN + 63) / 64, 256, 0, stream>>>(x, usd, xb, s_buf, d_buf, NN);
    fill_kernel<<<(EP + 255) / 256, 256, 0, stream>>>(ei, offsets, cursor, elist);

    // ---- Layer 1 (restructured): gather raw x, then block-diagonal GEMM ----
    gather_agg<<<(NN * 16 + 255) / 256, 256, 0, stream>>>(
        elist, offsets, xb, s_buf, d_buf, h_buf);
    gemm_bdiag<<<(NN + 63) / 64, 256, 0, stream>>>(h_buf, w1bf, b1, act_buf, NN);

    // ---- Layer 2: 512 -> 4 heads x 32 ----
    gemm_rows<512, 4, 32, __hip_bfloat16><<<(NN + 63) / 64, 256, 0, stream>>>(
        act_buf, w2bf, a2s, a2d, h_buf, s_buf, d_buf, NN);
    gather_fused<4, 32, 2><<<(NN * 64 + 255) / 256, 256, 0, stream>>>(
        elist, offsets, h_buf, s_buf, d_buf, b2, act_buf);

    // ---- Layer 3: 128 -> 1 head x 8 ----
    gemm8_kernel<<<(NN * 8 + 255) / 256, 256, 0, stream>>>(
        act_buf, W3, a3s, a3d, h_buf, s_buf, d_buf);
    gather_fused<1, 8, 8><<<(NN + 255) / 256, 256, 0, stream>>>(
        elist, offsets, h_buf, s_buf, d_buf, b3, act_buf);

    // ---- Final edge MLP ----
    mlp_kernel<<<(EE + 255) / 256, 256, 0, stream>>>(ei, act_buf, ea, yr, qt,
                                                     fc1w, fc1b, fc2w, fc2b, outp);
}

// Round 2
// 504.526 us; speedup vs baseline: 1.0862x; 1.0303x over previous
//
#include <hip/hip_runtime.h>
#include <hip/hip_bf16.h>

#define NN 50000
#define EE 400000
#define EP 450000   // EE + NN self-loops

typedef __attribute__((ext_vector_type(8))) short short8;
typedef __attribute__((ext_vector_type(4))) float f32x4;

__device__ __forceinline__ float bf2f(__hip_bfloat16 b) { return __bfloat162float(b); }
__device__ __forceinline__ float us2f(unsigned short u) {
    unsigned int x = ((unsigned int)u) << 16;
    union { unsigned int i; float f; } c; c.i = x; return c.f;
}
__device__ __forceinline__ unsigned short f2bfu(float f) {   // f32 -> bf16 bits, RNE
    union { float f; unsigned int u; } c; c.f = f;
    unsigned int r = c.u + 0x7FFFu + ((c.u >> 16) & 1u);
    return (unsigned short)(r >> 16);
}

// ---------------------------------------------------------------------------
// Weight pre-convert: W1 and W2 f32 -> bf16, one kernel.
// ---------------------------------------------------------------------------
__global__ void cvt2_kernel(const float* __restrict__ W1, const float* __restrict__ W2,
                            __hip_bfloat16* __restrict__ w1b, __hip_bfloat16* __restrict__ w2b) {
    int i = blockIdx.x * blockDim.x + threadIdx.x;
    if (i < 65536) w1b[i] = __float2bfloat16(W1[i]);
    else if (i < 131072) w2b[i - 65536] = __float2bfloat16(W2[i - 65536]);
}

// ---------------------------------------------------------------------------
// usd[row][k], row 0..3 = u_s per head, 4..7 = u_d per head (f32, exact):
//   u_s[h][k] = sum_c a1s[h][c] * W1[h*128+c][k]
// ---------------------------------------------------------------------------
__global__ void usd_kernel(const float* __restrict__ W1,
                           const float* __restrict__ a1s, const float* __restrict__ a1d,
                           float* __restrict__ usd) {
    int t = blockIdx.x * blockDim.x + threadIdx.x;
    if (t >= 1024) return;
    int row = t >> 7, k = t & 127;
    int hh = row & 3;
    const float* av = (row < 4) ? (a1s + hh * 128) : (a1d + hh * 128);
    const float* wp = W1 + (size_t)(hh * 128) * 128 + k;
    float acc = 0.f;
    for (int c = 0; c < 128; c++) acc += av[c] * wp[(size_t)c * 128];
    usd[t] = acc;
}

// ---------------------------------------------------------------------------
// Fused: x (f32) -> xb (bf16) convert + s1/d1 = x . usd (f32 dots, butterfly
// reduce over the 4 quads). One wave owns 16 rows, lane (r,quad) holds 32 cols.
// ---------------------------------------------------------------------------
__global__ void cvtx_sd(const float* __restrict__ x, const float* __restrict__ usd,
                        __hip_bfloat16* __restrict__ xb,
                        float* __restrict__ s, float* __restrict__ d, int M) {
    __shared__ float us_s[1024];
    for (int i = threadIdx.x; i < 1024; i += 256) us_s[i] = usd[i];
    __syncthreads();
    int wave = threadIdx.x >> 6, lane = threadIdx.x & 63;
    int m0 = blockIdx.x * 64 + wave * 16;
    int r = lane & 15, quad = lane >> 4;
    int am = m0 + r; if (am >= M) am = M - 1;
    const float* xp = x + (size_t)am * 128 + quad * 8;
    float xv[32];
#pragma unroll
    for (int kk = 0; kk < 4; kk++) {
        float4 a = *(const float4*)(xp + kk * 32);
        float4 bq = *(const float4*)(xp + kk * 32 + 4);
        xv[kk*8+0]=a.x;  xv[kk*8+1]=a.y;  xv[kk*8+2]=a.z;  xv[kk*8+3]=a.w;
        xv[kk*8+4]=bq.x; xv[kk*8+5]=bq.y; xv[kk*8+6]=bq.z; xv[kk*8+7]=bq.w;
        short8 o;
        o[0]=(short)f2bfu(a.x);  o[1]=(short)f2bfu(a.y);
        o[2]=(short)f2bfu(a.z);  o[3]=(short)f2bfu(a.w);
        o[4]=(short)f2bfu(bq.x); o[5]=(short)f2bfu(bq.y);
        o[6]=(short)f2bfu(bq.z); o[7]=(short)f2bfu(bq.w);
        *(short8*)(xb + (size_t)am * 128 + quad * 8 + kk * 32) = o;
    }
    float acc[8];
#pragma unroll
    for (int o = 0; o < 8; o++) {
        const float* up = us_s + o * 128 + quad * 8;
        float a = 0.f;
#pragma unroll
        for (int kk = 0; kk < 4; kk++)
#pragma unroll
            for (int j = 0; j < 8; j++) a += xv[kk*8+j] * up[kk*32+j];
        acc[o] = a;
    }
#pragma unroll
    for (int o = 0; o < 8; o++) {
        acc[o] += __shfl_xor(acc[o], 16, 64);
        acc[o] += __shfl_xor(acc[o], 32, 64);
    }
    int m = m0 + r;
    if (quad == 0 && m < M) {
#pragma unroll
        for (int hh = 0; hh < 4; hh++) { s[m*4+hh] = acc[hh]; d[m*4+hh] = acc[4+hh]; }
    }
}

// ---------------------------------------------------------------------------
// Layer-1 gather on RAW x (256B rows instead of 1KB h-rows).
// 16 lanes/node, each lane 8 x-channels, 4 head accumulators sharing the read.
// Writes NORMALIZED weighted sums aggn[n, hh*128+c] (bf16).
// ---------------------------------------------------------------------------
__global__ void gather_agg(const int* __restrict__ elist, const int* __restrict__ offsets,
                           const __hip_bfloat16* __restrict__ xb,
                           const float* __restrict__ s, const float* __restrict__ d,
                           __hip_bfloat16* __restrict__ aggn) {
    int gid = blockIdx.x * blockDim.x + threadIdx.x;
    if (gid >= NN * 16) return;
    int node = gid >> 4, t = gid & 15;
    int c0 = t * 8;
    int j0 = offsets[node], j1 = offsets[node + 1];
    float4 dv = *(const float4*)(d + node * 4);
    float den0=0.f, den1=0.f, den2=0.f, den3=0.f;
    float acc0[8], acc1[8], acc2[8], acc3[8];
#pragma unroll
    for (int c = 0; c < 8; c++) { acc0[c]=0.f; acc1[c]=0.f; acc2[c]=0.f; acc3[c]=0.f; }
    const unsigned short* hb = (const unsigned short*)xb;
    for (int j = j0; j < j1; j++) {
        int src = elist[j];
        float4 sv = *(const float4*)(s + src * 4);
        float e0 = sv.x + dv.x; e0 = e0 > 0.f ? e0 : 0.2f * e0; float w0 = __expf(e0); den0 += w0;
        float e1 = sv.y + dv.y; e1 = e1 > 0.f ? e1 : 0.2f * e1; float w1 = __expf(e1); den1 += w1;
        float e2 = sv.z + dv.z; e2 = e2 > 0.f ? e2 : 0.2f * e2; float w2 = __expf(e2); den2 += w2;
        float e3 = sv.w + dv.w; e3 = e3 > 0.f ? e3 : 0.2f * e3; float w3 = __expf(e3); den3 += w3;
        short8 xv = *(const short8*)(hb + (size_t)src * 128 + c0);
#pragma unroll
        for (int c = 0; c < 8; c++) {
            float xf = us2f((unsigned short)xv[c]);
            acc0[c] += w0 * xf; acc1[c] += w1 * xf;
            acc2[c] += w2 * xf; acc3[c] += w3 * xf;
        }
    }
    float i0 = 1.f/den0, i1 = 1.f/den1, i2 = 1.f/den2, i3 = 1.f/den3;
    __hip_bfloat16* op = aggn + (size_t)node * 512 + c0;
    short8 o0, o1, o2, o3;
#pragma unroll
    for (int c = 0; c < 8; c++) {
        o0[c] = (short)f2bfu(acc0[c]*i0); o1[c] = (short)f2bfu(acc1[c]*i1);
        o2[c] = (short)f2bfu(acc2[c]*i2); o3[c] = (short)f2bfu(acc3[c]*i3);
    }
    *(short8*)(op)       = o0;
    *(short8*)(op + 128) = o1;
    *(short8*)(op + 256) = o2;
    *(short8*)(op + 384) = o3;
}

// ---------------------------------------------------------------------------
// Block-diagonal GEMM for layer-1 output, wave-per-head for occupancy:
//   act[n, hh*128+oc] = ELU( sum_c aggn[n,hh,c] * W1[hh*128+oc, c] + b1 )
// Block = 4 waves = 16 rows x 4 heads. Grid = M/16 -> ~12 waves/SIMD demand.
// Per wave: 4 A-fragments, 8 n-tiles x 4 MFMA = 32 MFMAs.
// ---------------------------------------------------------------------------
__global__ void gemm_bdiag(const __hip_bfloat16* __restrict__ A,
                           const __hip_bfloat16* __restrict__ Wb,
                           const float* __restrict__ b,
                           __hip_bfloat16* __restrict__ act, int M) {
    int hh = threadIdx.x >> 6, lane = threadIdx.x & 63;
    int m0 = blockIdx.x * 16;
    int r = lane & 15, quad = lane >> 4;
    int am = m0 + r; if (am >= M) am = M - 1;
    short8 afrag[4];
    const __hip_bfloat16* arow = A + (size_t)am * 512 + hh * 128 + quad * 8;
#pragma unroll
    for (int kk = 0; kk < 4; kk++) afrag[kk] = *(const short8*)(arow + kk * 32);
    const __hip_bfloat16* wrow = Wb + (size_t)(hh * 128 + r) * 128 + quad * 8;
#pragma unroll
    for (int nb = 0; nb < 128; nb += 16) {
        f32x4 acc = {0.f, 0.f, 0.f, 0.f};
#pragma unroll
        for (int kk = 0; kk < 4; kk++) {
            short8 bfr = *(const short8*)(wrow + (size_t)nb * 128 + kk * 32);
            acc = __builtin_amdgcn_mfma_f32_16x16x32_bf16(afrag[kk], bfr, acc, 0, 0, 0);
        }
        int n0 = hh * 128 + nb;
        float bias = b[n0 + r];
#pragma unroll
        for (int i = 0; i < 4; i++) {
            int m = m0 + quad * 4 + i;
            if (m < M) {
                float v = acc[i] + bias;
                v = v > 0.f ? v : (__expf(v) - 1.0f);
                act[(size_t)m * 512 + n0 + r] = __float2bfloat16(v);
            }
        }
    }
}

// ---------------------------------------------------------------------------
// Layer-2 GEMM, wave-per-head: h2[n, hh*32+oc] = sum_k act1[n,k]*W2[hh*32+oc,k]
// + fused s2/d2 attention-coefficient epilogue (butterfly over 16 r-lanes).
// Block = 4 waves = 16 rows x 4 heads; per wave 2 n-tiles x 16 k = 32 MFMAs.
// ---------------------------------------------------------------------------
__global__ void gemm_l2(const __hip_bfloat16* __restrict__ A,
                        const __hip_bfloat16* __restrict__ Wb,
                        const float* __restrict__ as_, const float* __restrict__ ad_,
                        __hip_bfloat16* __restrict__ Cb,
                        float* __restrict__ s, float* __restrict__ d, int M) {
    int hh = threadIdx.x >> 6, lane = threadIdx.x & 63;
    int m0 = blockIdx.x * 16;
    int r = lane & 15, quad = lane >> 4;
    int am = m0 + r; if (am >= M) am = M - 1;
    short8 afrag[16];
    const __hip_bfloat16* arow = A + (size_t)am * 512 + quad * 8;
#pragma unroll
    for (int kk = 0; kk < 16; kk++) afrag[kk] = *(const short8*)(arow + kk * 32);
    const __hip_bfloat16* wrow = Wb + (size_t)r * 512 + quad * 8;
    float sacc[4] = {0.f, 0.f, 0.f, 0.f};
    float dacc[4] = {0.f, 0.f, 0.f, 0.f};
#pragma unroll
    for (int t = 0; t < 2; t++) {
        int n0 = hh * 32 + t * 16;
        f32x4 acc = {0.f, 0.f, 0.f, 0.f};
#pragma unroll
        for (int kk = 0; kk < 16; kk++) {
            short8 bfr = *(const short8*)(wrow + (size_t)n0 * 512 + kk * 32);
            acc = __builtin_amdgcn_mfma_f32_16x16x32_bf16(afrag[kk], bfr, acc, 0, 0, 0);
        }
        float as_v = as_[n0 + r];
        float ad_v = ad_[n0 + r];
        // C/D layout: col = lane&15 (n), row = quad*4 + i (m)
#pragma unroll
        for (int i = 0; i < 4; i++) {
            int m = m0 + quad * 4 + i;
            if (m < M) Cb[(size_t)m * 128 + n0 + r] = __float2bfloat16(acc[i]);
            sacc[i] += acc[i] * as_v;
            dacc[i] += acc[i] * ad_v;
        }
    }
#pragma unroll
    for (int mask = 1; mask <= 8; mask <<= 1) {
#pragma unroll
        for (int i = 0; i < 4; i++) {
            sacc[i] += __shfl_xor(sacc[i], mask, 64);
            dacc[i] += __shfl_xor(dacc[i], mask, 64);
        }
    }
    if (r == 0) {
#pragma unroll
        for (int i = 0; i < 4; i++) {
            int m = m0 + quad * 4 + i;
            if (m < M) { s[m * 4 + hh] = sacc[i]; d[m * 4 + hh] = dacc[i]; }
        }
    }
}

// ---------------------------------------------------------------------------
// Tiny GEMM for layer 3 + fused s/d. Split-K: 8 lanes per node, lane t owns
// k-slice [t*16, t*16+16) for ALL 8 outputs; coalesced vector loads;
// butterfly reduce over the 8 lanes.
// ---------------------------------------------------------------------------
__global__ void gemm8_kernel(const __hip_bfloat16* __restrict__ A,
                             const float* __restrict__ W,
                             const float* __restrict__ a3s, const float* __restrict__ a3d,
                             __hip_bfloat16* __restrict__ Cb,
                             float* __restrict__ s, float* __restrict__ d) {
    int gid = blockIdx.x * blockDim.x + threadIdx.x;
    if (gid >= NN * 8) return;
    int n = gid >> 3, t = gid & 7;
    const unsigned short* ap = (const unsigned short*)A + (size_t)n * 128 + t * 16;
    short8 v0 = *(const short8*)ap;
    short8 v1 = *(const short8*)(ap + 8);
    float xf[16];
#pragma unroll
    for (int j = 0; j < 8; j++) { xf[j] = us2f((unsigned short)v0[j]); xf[8+j] = us2f((unsigned short)v1[j]); }
    float acc[8];
#pragma unroll
    for (int c = 0; c < 8; c++) {
        const float* wp = W + c * 128 + t * 16;
        float a = 0.f;
#pragma unroll
        for (int j = 0; j < 16; j++) a += xf[j] * wp[j];
        acc[c] = a;
    }
#pragma unroll
    for (int mask = 1; mask <= 4; mask <<= 1)
#pragma unroll
        for (int c = 0; c < 8; c++) acc[c] += __shfl_xor(acc[c], mask, 64);
    // every lane now holds all 8 dots
    Cb[n * 8 + t] = __float2bfloat16(acc[t]);
    if (t == 0) {
        float sv = 0.f, dvv = 0.f;
#pragma unroll
        for (int c = 0; c < 8; c++) { sv += acc[c] * a3s[c]; dvv += acc[c] * a3d[c]; }
        s[n] = sv; d[n] = dvv;
    }
}

// ---------------------------------------------------------------------------
// CSR build: deg histogram -> single-block scan -> fill (dst-sorted src list)
// ---------------------------------------------------------------------------
__global__ void deg_kernel(const int* __restrict__ ei, int* __restrict__ deg) {
    int e = blockIdx.x * blockDim.x + threadIdx.x;
    if (e >= EP) return;
    int dst = (e < EE) ? ei[EE + e] : e - EE;
    atomicAdd(&deg[dst], 1);
}

#define SCAN_T 1024
__global__ void scan_kernel(const int* __restrict__ deg, int* __restrict__ offsets) {
    __shared__ int part[SCAN_T];
    int t = threadIdx.x;
    constexpr int CHUNK = (NN + SCAN_T - 1) / SCAN_T;   // 49
    int lo = t * CHUNK;
    int hi = lo + CHUNK; if (hi > NN) hi = NN;
    int s = 0;
    for (int i = lo; i < hi && i < NN; i++) s += deg[i];
    part[t] = s;
    __syncthreads();
    for (int off = 1; off < SCAN_T; off <<= 1) {
        int v = (t >= off) ? part[t - off] : 0;
        __syncthreads();
        part[t] += v;
        __syncthreads();
    }
    int run = (t == 0) ? 0 : part[t - 1];
    for (int i = lo; i < hi && i < NN; i++) { offsets[i] = run; run += deg[i]; }
    if (t == SCAN_T - 1) offsets[NN] = run;
}

__global__ void fill_kernel(const int* __restrict__ ei, const int* __restrict__ offsets,
                            int* __restrict__ cursor, int* __restrict__ elist) {
    int e = blockIdx.x * blockDim.x + threadIdx.x;
    if (e >= EP) return;
    int src, dst;
    if (e < EE) { src = ei[e]; dst = ei[EE + e]; } else { src = dst = e - EE; }
    int pos = atomicAdd(&cursor[dst], 1);
    elist[offsets[dst] + pos] = src;
}

// ---------------------------------------------------------------------------
// Fused gather (layers 2,3): w_e = exp(leaky_relu(s[src]+d[node])) inline;
// out[n,c] = (sum_e w_e * h[src_e,c]) / (sum_e w_e); + bias, ELU -> bf16.
// ---------------------------------------------------------------------------
template<int H, int C, int CPL>
__global__ void gather_fused(const int* __restrict__ elist,
                             const int* __restrict__ offsets,
                             const __hip_bfloat16* __restrict__ h,
                             const float* __restrict__ s, const float* __restrict__ d,
                             const float* __restrict__ b,
                             __hip_bfloat16* __restrict__ act) {
    constexpr int HC = H * C;
    constexpr int TPN = HC / CPL;
    int gid = blockIdx.x * blockDim.x + threadIdx.x;
    if (gid >= NN * TPN) return;
    int node = gid / TPN;
    int t = gid - node * TPN;
    int c0 = t * CPL;
    int hh = c0 / C;
    int j0 = offsets[node], j1 = offsets[node + 1];
    float dv = d[node * H + hh];
    float den = 0.f;
    float acc[CPL];
#pragma unroll
    for (int c = 0; c < CPL; c++) acc[c] = 0.f;
    const unsigned short* hb = (const unsigned short*)h;
    for (int j = j0; j < j1; j++) {
        int src = elist[j];
        float x = s[src * H + hh] + dv;
        x = x > 0.f ? x : 0.2f * x;
        float w = __expf(x);
        den += w;
        const unsigned short* hp = hb + (size_t)src * HC + c0;
        if constexpr (CPL == 8) {
            short8 a8 = *(const short8*)hp;
#pragma unroll
            for (int c = 0; c < 8; c++) acc[c] += w * us2f((unsigned short)a8[c]);
        } else {
            ushort2 a = *(const ushort2*)hp;
            acc[0] += w * us2f(a.x);
            acc[1] += w * us2f(a.y);
        }
    }
    float inv = 1.0f / den;   // deg >= 1 (self-loop), den > 0
    __hip_bfloat16* op = act + (size_t)node * HC + c0;
#pragma unroll
    for (int c = 0; c < CPL; c++) {
        float v = acc[c] * inv + b[c0 + c];
        v = v > 0.f ? v : (__expf(v) - 1.0f);
        op[c] = __float2bfloat16(v);
    }
}

// ---------------------------------------------------------------------------
// Final edge MLP: z[19] = [h3[src], h3[dst], ea, yr, qt] -> fc1(relu) -> fc2
// ---------------------------------------------------------------------------
__global__ void mlp_kernel(const int* __restrict__ ei,
                           const __hip_bfloat16* __restrict__ act3,
                           const float* __restrict__ ea,
                           const float* __restrict__ yr,
                           const float* __restrict__ qt,
                           const float* __restrict__ fc1w,
                           const float* __restrict__ fc1b,
                           const float* __restrict__ fc2w,
                           const float* __restrict__ fc2b,
                           float* __restrict__ outp) {
    __shared__ float w1[16 * 19], b1s[16], w2[16];
    for (int i = threadIdx.x; i < 16 * 19; i += blockDim.x) w1[i] = fc1w[i];
    if (threadIdx.x < 16) {
        b1s[threadIdx.x] = fc1b[threadIdx.x];
        w2[threadIdx.x] = fc2w[threadIdx.x];
    }
    __syncthreads();
    int e = blockIdx.x * blockDim.x + threadIdx.x;
    if (e >= EE) return;
    int src = ei[e], dst = ei[EE + e];
    float z[19];
#pragma unroll
    for (int i = 0; i < 8; i++) z[i] = bf2f(act3[src * 8 + i]);
#pragma unroll
    for (int i = 0; i < 8; i++) z[8 + i] = bf2f(act3[dst * 8 + i]);
    z[16] = ea[e]; z[17] = yr[e]; z[18] = qt[e];
    float acc2 = fc2b[0];
#pragma unroll
    for (int j = 0; j < 16; j++) {
        float a = b1s[j];
#pragma unroll
        for (int i = 0; i < 19; i++) a += z[i] * w1[j * 19 + i];
        a = a > 0.f ? a : 0.f;
        acc2 += a * w2[j];
    }
    outp[e] = acc2;
}

// ---------------------------------------------------------------------------
extern "C" void kernel_launch(void* const* d_in, const int* in_sizes, int n_in,
                              void* d_out, int out_size, void* d_ws, size_t ws_size,
                              hipStream_t stream) {
    const float* x    = (const float*)d_in[0];
    const int*   ei   = (const int*)d_in[1];
    const float* ea   = (const float*)d_in[2];
    const float* yr   = (const float*)d_in[3];
    const float* qt   = (const float*)d_in[4];
    const float* W1   = (const float*)d_in[5];
    const float* a1s  = (const float*)d_in[6];
    const float* a1d  = (const float*)d_in[7];
    const float* b1   = (const float*)d_in[8];
    const float* W2   = (const float*)d_in[9];
    const float* a2s  = (const float*)d_in[10];
    const float* a2d  = (const float*)d_in[11];
    const float* b2   = (const float*)d_in[12];
    const float* W3   = (const float*)d_in[13];
    const float* a3s  = (const float*)d_in[14];
    const float* a3d  = (const float*)d_in[15];
    const float* b3   = (const float*)d_in[16];
    const float* fc1w = (const float*)d_in[17];
    const float* fc1b = (const float*)d_in[18];
    const float* fc2w = (const float*)d_in[19];
    const float* fc2b = (const float*)d_in[20];
    float* outp = (float*)d_out;

    char* ws = (char*)d_ws;
    __hip_bfloat16* h_buf   = (__hip_bfloat16*)(ws);                 // N*512 bf16 (51.2 MB): aggn / h2 / h3
    __hip_bfloat16* act_buf = (__hip_bfloat16*)(ws + 51200000);      // N*512 bf16 (51.2 MB): xb / act1 / act2 / act3
    float* s_buf   = (float*)(ws + 102400000);                       // N*4 f32
    float* d_buf   = (float*)(ws + 103200000);                       // N*4 f32
    int*   deg     = (int*)  (ws + 104000000);                       // N ints
    int*   cursor  = (int*)  (ws + 104200000);                       // N ints (contiguous w/ deg)
    int*   offsets = (int*)  (ws + 104400000);                       // N+1 ints
    int*   elist   = (int*)  (ws + 104600016);                       // EP ints (1.8 MB)
    __hip_bfloat16* w1bf = (__hip_bfloat16*)(ws + 106400016);        // 512*128 bf16
    __hip_bfloat16* w2bf = (__hip_bfloat16*)(ws + 106531088);        // 128*512 bf16
    float* usd = (float*)(ws + 106662160);                           // 8*128 f32 (4 KB)
    __hip_bfloat16* xb = act_buf;                                    // N*128 bf16, dead after gather_agg

    // ---- CSR build + weight pre-convert + u-vector precompute ----
    hipMemsetAsync(deg, 0, 2 * NN * sizeof(int), stream);            // deg + cursor
    deg_kernel<<<(EP + 255) / 256, 256, 0, stream>>>(ei, deg);
    cvt2_kernel<<<(131072 + 255) / 256, 256, 0, stream>>>(W1, W2, w1bf, w2bf);
    usd_kernel<<<4, 256, 0, stream>>>(W1, a1s, a1d, usd);
    scan_kernel<<<1, SCAN_T, 0, stream>>>(deg, offsets);
    cvtx_sd<<<(NN + 63) / 64, 256, 0, stream>>>(x, usd, xb, s_buf, d_buf, NN);
    fill_kernel<<<(EP + 255) / 256, 256, 0, stream>>>(ei, offsets, cursor, elist);

    // ---- Layer 1 (restructured): gather raw x, then block-diagonal GEMM ----
    gather_agg<<<(NN * 16 + 255) / 256, 256, 0, stream>>>(
        elist, offsets, xb, s_buf, d_buf, h_buf);
    gemm_bdiag<<<(NN + 15) / 16, 256, 0, stream>>>(h_buf, w1bf, b1, act_buf, NN);

    // ---- Layer 2: 512 -> 4 heads x 32 ----
    gemm_l2<<<(NN + 15) / 16, 256, 0, stream>>>(
        act_buf, w2bf, a2s, a2d, h_buf, s_buf, d_buf, NN);
    gather_fused<4, 32, 2><<<(NN * 64 + 255) / 256, 256, 0, stream>>>(
        elist, offsets, h_buf, s_buf, d_buf, b2, act_buf);

    // ---- Layer 3: 128 -> 1 head x 8 ----
    gemm8_kernel<<<(NN * 8 + 255) / 256, 256, 0, stream>>>(
        act_buf, W3, a3s, a3d, h_buf, s_buf, d_buf);
    gather_fused<1, 8, 8><<<(NN + 255) / 256, 256, 0, stream>>>(
        elist, offsets, h_buf, s_buf, d_buf, b3, act_buf);

    // ---- Final edge MLP ----
    mlp_kernel<<<(EE + 255) / 256, 256, 0, stream>>>(ei, act_buf, ea, yr, qt,
                                                     fc1w, fc1b, fc2w, fc2b, outp);
}

// Round 3
// 365.766 us; speedup vs baseline: 1.4983x; 1.3794x over previous
//
#include <hip/hip_runtime.h>
#include <hip/hip_bf16.h>

#define NN 50000
#define EE 400000
#define EP 450000   // EE + NN self-loops

typedef __attribute__((ext_vector_type(8))) short short8;
typedef __attribute__((ext_vector_type(4))) float f32x4;

__device__ __forceinline__ float bf2f(__hip_bfloat16 b) { return __bfloat162float(b); }
__device__ __forceinline__ float us2f(unsigned short u) {
    unsigned int x = ((unsigned int)u) << 16;
    union { unsigned int i; float f; } c; c.i = x; return c.f;
}
__device__ __forceinline__ unsigned short f2bfu(float f) {   // f32 -> bf16 bits, RNE
    union { float f; unsigned int u; } c; c.f = f;
    unsigned int r = c.u + 0x7FFFu + ((c.u >> 16) & 1u);
    return (unsigned short)(r >> 16);
}

// Packed MFMA-fragment index for a [M x K] bf16 matrix consumed as A (or B with
// n in place of m) by mfma_f32_16x16x32_bf16:
//   idx(m,k) = ((m>>4)*(K/32) + (k>>5))*512 + ((k&31)>>3)*128 + (m&15)*8 + (k&7)
// A wave's fragment load is then (fragbase + lane*8): 1KB fully contiguous.

// ---------------------------------------------------------------------------
// Weight pre-convert + PACK: W1 (512x128) and W2 (128x512) f32 -> bf16 frags.
// ---------------------------------------------------------------------------
__global__ void cvt2_kernel(const float* __restrict__ W1, const float* __restrict__ W2,
                            __hip_bfloat16* __restrict__ pw1, __hip_bfloat16* __restrict__ pw2) {
    int i = blockIdx.x * blockDim.x + threadIdx.x;
    if (i < 65536) {
        int n = i >> 7, k = i & 127;   // K=128, NK=4
        int idx = ((n >> 4) * 4 + (k >> 5)) * 512 + ((k & 31) >> 3) * 128 + (n & 15) * 8 + (k & 7);
        pw1[idx] = __float2bfloat16(W1[i]);
    } else if (i < 131072) {
        int j = i - 65536;
        int n = j >> 9, k = j & 511;   // K=512, NK=16
        int idx = ((n >> 4) * 16 + (k >> 5)) * 512 + ((k & 31) >> 3) * 128 + (n & 15) * 8 + (k & 7);
        pw2[idx] = __float2bfloat16(W2[j]);
    }
}

// ---------------------------------------------------------------------------
// usd[row][k], row 0..3 = u_s per head, 4..7 = u_d per head (f32, exact):
//   u_s[h][k] = sum_c a1s[h][c] * W1[h*128+c][k]
// ---------------------------------------------------------------------------
__global__ void usd_kernel(const float* __restrict__ W1,
                           const float* __restrict__ a1s, const float* __restrict__ a1d,
                           float* __restrict__ usd) {
    int t = blockIdx.x * blockDim.x + threadIdx.x;
    if (t >= 1024) return;
    int row = t >> 7, k = t & 127;
    int hh = row & 3;
    const float* av = (row < 4) ? (a1s + hh * 128) : (a1d + hh * 128);
    const float* wp = W1 + (size_t)(hh * 128) * 128 + k;
    float acc = 0.f;
    for (int c = 0; c < 128; c++) acc += av[c] * wp[(size_t)c * 128];
    usd[t] = acc;
}

// ---------------------------------------------------------------------------
// Fused: x (f32) -> xb (bf16) convert + s1/d1 = x . usd (f32 dots, butterfly
// reduce over the 4 quads). One wave owns 16 rows, lane (r,quad) holds 32 cols.
// ---------------------------------------------------------------------------
__global__ void cvtx_sd(const float* __restrict__ x, const float* __restrict__ usd,
                        __hip_bfloat16* __restrict__ xb,
                        float* __restrict__ s, float* __restrict__ d, int M) {
    __shared__ float us_s[1024];
    for (int i = threadIdx.x; i < 1024; i += 256) us_s[i] = usd[i];
    __syncthreads();
    int wave = threadIdx.x >> 6, lane = threadIdx.x & 63;
    int m0 = blockIdx.x * 64 + wave * 16;
    int r = lane & 15, quad = lane >> 4;
    int am = m0 + r; if (am >= M) am = M - 1;
    const float* xp = x + (size_t)am * 128 + quad * 8;
    float xv[32];
#pragma unroll
    for (int kk = 0; kk < 4; kk++) {
        float4 a = *(const float4*)(xp + kk * 32);
        float4 bq = *(const float4*)(xp + kk * 32 + 4);
        xv[kk*8+0]=a.x;  xv[kk*8+1]=a.y;  xv[kk*8+2]=a.z;  xv[kk*8+3]=a.w;
        xv[kk*8+4]=bq.x; xv[kk*8+5]=bq.y; xv[kk*8+6]=bq.z; xv[kk*8+7]=bq.w;
        short8 o;
        o[0]=(short)f2bfu(a.x);  o[1]=(short)f2bfu(a.y);
        o[2]=(short)f2bfu(a.z);  o[3]=(short)f2bfu(a.w);
        o[4]=(short)f2bfu(bq.x); o[5]=(short)f2bfu(bq.y);
        o[6]=(short)f2bfu(bq.z); o[7]=(short)f2bfu(bq.w);
        *(short8*)(xb + (size_t)am * 128 + quad * 8 + kk * 32) = o;
    }
    float acc[8];
#pragma unroll
    for (int o = 0; o < 8; o++) {
        const float* up = us_s + o * 128 + quad * 8;
        float a = 0.f;
#pragma unroll
        for (int kk = 0; kk < 4; kk++)
#pragma unroll
            for (int j = 0; j < 8; j++) a += xv[kk*8+j] * up[kk*32+j];
        acc[o] = a;
    }
#pragma unroll
    for (int o = 0; o < 8; o++) {
        acc[o] += __shfl_xor(acc[o], 16, 64);
        acc[o] += __shfl_xor(acc[o], 32, 64);
    }
    int m = m0 + r;
    if (quad == 0 && m < M) {
#pragma unroll
        for (int hh = 0; hh < 4; hh++) { s[m*4+hh] = acc[hh]; d[m*4+hh] = acc[4+hh]; }
    }
}

// ---------------------------------------------------------------------------
// Layer-1 gather on RAW x. 16 lanes/node, each lane 8 x-channels, 4 head
// accumulators sharing the read. Writes PACKED fragments for gemm_bdiag:
// element (node, kglob=hh*128+t*8+slot): frag=(node>>4)*16+hh*4+(t>>2),
// sub=t&3 -> each short8 is one contiguous 16B slot-run.
// ---------------------------------------------------------------------------
__global__ void gather_agg(const int* __restrict__ elist, const int* __restrict__ offsets,
                           const __hip_bfloat16* __restrict__ xb,
                           const float* __restrict__ s, const float* __restrict__ d,
                           __hip_bfloat16* __restrict__ pagg) {
    int gid = blockIdx.x * blockDim.x + threadIdx.x;
    if (gid >= NN * 16) return;
    int node = gid >> 4, t = gid & 15;
    int c0 = t * 8;
    int j0 = offsets[node], j1 = offsets[node + 1];
    float4 dv = *(const float4*)(d + node * 4);
    float den0=0.f, den1=0.f, den2=0.f, den3=0.f;
    float acc0[8], acc1[8], acc2[8], acc3[8];
#pragma unroll
    for (int c = 0; c < 8; c++) { acc0[c]=0.f; acc1[c]=0.f; acc2[c]=0.f; acc3[c]=0.f; }
    const unsigned short* hb = (const unsigned short*)xb;
    for (int j = j0; j < j1; j++) {
        int src = elist[j];
        float4 sv = *(const float4*)(s + src * 4);
        float e0 = sv.x + dv.x; e0 = e0 > 0.f ? e0 : 0.2f * e0; float w0 = __expf(e0); den0 += w0;
        float e1 = sv.y + dv.y; e1 = e1 > 0.f ? e1 : 0.2f * e1; float w1 = __expf(e1); den1 += w1;
        float e2 = sv.z + dv.z; e2 = e2 > 0.f ? e2 : 0.2f * e2; float w2 = __expf(e2); den2 += w2;
        float e3 = sv.w + dv.w; e3 = e3 > 0.f ? e3 : 0.2f * e3; float w3 = __expf(e3); den3 += w3;
        short8 xv = *(const short8*)(hb + (size_t)src * 128 + c0);
#pragma unroll
        for (int c = 0; c < 8; c++) {
            float xf = us2f((unsigned short)xv[c]);
            acc0[c] += w0 * xf; acc1[c] += w1 * xf;
            acc2[c] += w2 * xf; acc3[c] += w3 * xf;
        }
    }
    float i0 = 1.f/den0, i1 = 1.f/den1, i2 = 1.f/den2, i3 = 1.f/den3;
    short8 o0, o1, o2, o3;
#pragma unroll
    for (int c = 0; c < 8; c++) {
        o0[c] = (short)f2bfu(acc0[c]*i0); o1[c] = (short)f2bfu(acc1[c]*i1);
        o2[c] = (short)f2bfu(acc2[c]*i2); o3[c] = (short)f2bfu(acc3[c]*i3);
    }
    // packed write: base covers tile + sub + row-in-tile; per head add frag*512
    __hip_bfloat16* base = pagg + ((size_t)(node >> 4) * 16) * 512
                         + (t & 3) * 128 + (node & 15) * 8;
    int fo = (t >> 2) * 512;
    *(short8*)(base + fo)            = o0;   // hh=0: frag hh*4+(t>>2)
    *(short8*)(base + fo + 4 * 512)  = o1;   // hh=1
    *(short8*)(base + fo + 8 * 512)  = o2;   // hh=2
    *(short8*)(base + fo + 12 * 512) = o3;   // hh=3
}

// ---------------------------------------------------------------------------
// Block-diagonal GEMM for layer-1 output, wave-per-head, packed in/out:
//   act[n, hh*128+oc] = ELU( sum_c aggn[n,hh,c] * W1[hh*128+oc, c] + b1 )
// All fragment loads are contiguous 1KB/wave. Output written PACKED (K=512)
// for gemm_l2's A-side.
// ---------------------------------------------------------------------------
__global__ void gemm_bdiag(const __hip_bfloat16* __restrict__ pA,
                           const __hip_bfloat16* __restrict__ pW1,
                           const float* __restrict__ b,
                           __hip_bfloat16* __restrict__ pact, int M) {
    int hh = threadIdx.x >> 6, lane = threadIdx.x & 63;
    int m0 = blockIdx.x * 16;
    int r = lane & 15, quad = lane >> 4;
    short8 afrag[4];
    const __hip_bfloat16* ap = pA + ((size_t)(m0 >> 4) * 16 + hh * 4) * 512 + lane * 8;
#pragma unroll
    for (int kk = 0; kk < 4; kk++) afrag[kk] = *(const short8*)(ap + kk * 512);
#pragma unroll
    for (int nb = 0; nb < 128; nb += 16) {
        const __hip_bfloat16* bp = pW1 + ((size_t)(hh * 8 + (nb >> 4)) * 4) * 512 + lane * 8;
        f32x4 acc = {0.f, 0.f, 0.f, 0.f};
#pragma unroll
        for (int kk = 0; kk < 4; kk++) {
            short8 bfr = *(const short8*)(bp + kk * 512);
            acc = __builtin_amdgcn_mfma_f32_16x16x32_bf16(afrag[kk], bfr, acc, 0, 0, 0);
        }
        int n0 = hh * 128 + nb;
        float bias = b[n0 + r];
        // packed store: k = n0 + r, m = m0 + quad*4 + i
        int kk2 = (n0 + r) >> 5;
        int sub = ((nb & 16) + r) >> 3;
        __hip_bfloat16* op = pact + ((size_t)(m0 >> 4) * 16 + kk2) * 512
                           + sub * 128 + (r & 7);
#pragma unroll
        for (int i = 0; i < 4; i++) {
            float v = acc[i] + bias;
            v = v > 0.f ? v : (__expf(v) - 1.0f);
            op[(quad * 4 + i) * 8] = __float2bfloat16(v);
        }
    }
}

// ---------------------------------------------------------------------------
// Layer-2 GEMM, wave-per-head, packed A and W; streams af/b0/b1 per k (2 MFMA
// per A-load, ~40 VGPR). Fused s2/d2 epilogue. h2 written row-major [N][128].
// ---------------------------------------------------------------------------
__global__ void gemm_l2(const __hip_bfloat16* __restrict__ pA,
                        const __hip_bfloat16* __restrict__ pW2,
                        const float* __restrict__ as_, const float* __restrict__ ad_,
                        __hip_bfloat16* __restrict__ Cb,
                        float* __restrict__ s, float* __restrict__ d, int M) {
    int hh = threadIdx.x >> 6, lane = threadIdx.x & 63;
    int m0 = blockIdx.x * 16;
    int r = lane & 15, quad = lane >> 4;
    const __hip_bfloat16* ap  = pA + (size_t)(m0 >> 4) * 16 * 512 + lane * 8;
    const __hip_bfloat16* bp0 = pW2 + (size_t)(hh * 2) * 16 * 512 + lane * 8;
    const __hip_bfloat16* bp1 = bp0 + 16 * 512;
    f32x4 acc0 = {0.f, 0.f, 0.f, 0.f}, acc1 = {0.f, 0.f, 0.f, 0.f};
#pragma unroll
    for (int kk = 0; kk < 16; kk++) {
        short8 af = *(const short8*)(ap + kk * 512);
        short8 b0 = *(const short8*)(bp0 + kk * 512);
        short8 b1 = *(const short8*)(bp1 + kk * 512);
        acc0 = __builtin_amdgcn_mfma_f32_16x16x32_bf16(af, b0, acc0, 0, 0, 0);
        acc1 = __builtin_amdgcn_mfma_f32_16x16x32_bf16(af, b1, acc1, 0, 0, 0);
    }
    int n0 = hh * 32;
    float as0 = as_[n0 + r],      ad0 = ad_[n0 + r];
    float as1 = as_[n0 + 16 + r], ad1 = ad_[n0 + 16 + r];
    float sacc[4], dacc[4];
#pragma unroll
    for (int i = 0; i < 4; i++) {
        int m = m0 + quad * 4 + i;
        Cb[(size_t)m * 128 + n0 + r]      = __float2bfloat16(acc0[i]);
        Cb[(size_t)m * 128 + n0 + 16 + r] = __float2bfloat16(acc1[i]);
        sacc[i] = acc0[i] * as0 + acc1[i] * as1;
        dacc[i] = acc0[i] * ad0 + acc1[i] * ad1;
    }
#pragma unroll
    for (int mask = 1; mask <= 8; mask <<= 1) {
#pragma unroll
        for (int i = 0; i < 4; i++) {
            sacc[i] += __shfl_xor(sacc[i], mask, 64);
            dacc[i] += __shfl_xor(dacc[i], mask, 64);
        }
    }
    if (r == 0) {
#pragma unroll
        for (int i = 0; i < 4; i++) {
            int m = m0 + quad * 4 + i;
            s[m * 4 + hh] = sacc[i]; d[m * 4 + hh] = dacc[i];
        }
    }
}

// ---------------------------------------------------------------------------
// Tiny GEMM for layer 3 + fused s/d. Split-K: 8 lanes per node, lane t owns
// k-slice [t*16, t*16+16) for ALL 8 outputs; butterfly reduce over 8 lanes.
// ---------------------------------------------------------------------------
__global__ void gemm8_kernel(const __hip_bfloat16* __restrict__ A,
                             const float* __restrict__ W,
                             const float* __restrict__ a3s, const float* __restrict__ a3d,
                             __hip_bfloat16* __restrict__ Cb,
                             float* __restrict__ s, float* __restrict__ d) {
    int gid = blockIdx.x * blockDim.x + threadIdx.x;
    if (gid >= NN * 8) return;
    int n = gid >> 3, t = gid & 7;
    const unsigned short* ap = (const unsigned short*)A + (size_t)n * 128 + t * 16;
    short8 v0 = *(const short8*)ap;
    short8 v1 = *(const short8*)(ap + 8);
    float xf[16];
#pragma unroll
    for (int j = 0; j < 8; j++) { xf[j] = us2f((unsigned short)v0[j]); xf[8+j] = us2f((unsigned short)v1[j]); }
    float acc[8];
#pragma unroll
    for (int c = 0; c < 8; c++) {
        const float* wp = W + c * 128 + t * 16;
        float a = 0.f;
#pragma unroll
        for (int j = 0; j < 16; j++) a += xf[j] * wp[j];
        acc[c] = a;
    }
#pragma unroll
    for (int mask = 1; mask <= 4; mask <<= 1)
#pragma unroll
        for (int c = 0; c < 8; c++) acc[c] += __shfl_xor(acc[c], mask, 64);
    Cb[n * 8 + t] = __float2bfloat16(acc[t]);
    if (t == 0) {
        float sv = 0.f, dvv = 0.f;
#pragma unroll
        for (int c = 0; c < 8; c++) { sv += acc[c] * a3s[c]; dvv += acc[c] * a3d[c]; }
        s[n] = sv; d[n] = dvv;
    }
}

// ---------------------------------------------------------------------------
// CSR build: deg histogram -> two-level multi-block scan -> fill
// ---------------------------------------------------------------------------
__global__ void deg_kernel(const int* __restrict__ ei, int* __restrict__ deg) {
    int e = blockIdx.x * blockDim.x + threadIdx.x;
    if (e >= EP) return;
    int dst = (e < EE) ? ei[EE + e] : e - EE;
    atomicAdd(&deg[dst], 1);
}

#define SCB 49   // scan blocks, 1024 elements each (49*1024 = 50176 >= NN)
__global__ void scan1_kernel(const int* __restrict__ deg, int* __restrict__ bsum) {
    __shared__ int red[256];
    int b = blockIdx.x, t = threadIdx.x;
    int base = b * 1024 + t * 4;
    int s = 0;
    if (base + 3 < NN) { int4 v = *(const int4*)(deg + base); s = v.x + v.y + v.z + v.w; }
    else { for (int i = base; i < NN; i++) s += deg[i]; }
    red[t] = s;
    __syncthreads();
    for (int off = 128; off > 0; off >>= 1) {
        if (t < off) red[t] += red[t + off];
        __syncthreads();
    }
    if (t == 0) bsum[b] = red[0];
}

__global__ void scan2_kernel(const int* __restrict__ deg, const int* __restrict__ bsum,
                             int* __restrict__ offsets) {
    __shared__ int lsum[256];
    int b = blockIdx.x, t = threadIdx.x;
    int boff = 0;
    for (int i = 0; i < b; i++) boff += bsum[i];       // <=48 cached loads
    int base = b * 1024 + t * 4;
    int4 v = {0, 0, 0, 0};
    if (base + 3 < NN) v = *(const int4*)(deg + base);
    else {
        if (base < NN)     v.x = deg[base];
        if (base + 1 < NN) v.y = deg[base + 1];
        if (base + 2 < NN) v.z = deg[base + 2];
        if (base + 3 < NN) v.w = deg[base + 3];
    }
    int s = v.x + v.y + v.z + v.w;
    lsum[t] = s;
    __syncthreads();
    for (int off = 1; off < 256; off <<= 1) {
        int val = (t >= off) ? lsum[t - off] : 0;
        __syncthreads();
        lsum[t] += val;
        __syncthreads();
    }
    int ex = boff + (t ? lsum[t - 1] : 0);
    if (base < NN)     offsets[base]     = ex;
    if (base + 1 < NN) offsets[base + 1] = ex + v.x;
    if (base + 2 < NN) offsets[base + 2] = ex + v.x + v.y;
    if (base + 3 < NN) offsets[base + 3] = ex + v.x + v.y + v.z;
    if (b == SCB - 1 && t == 255) offsets[NN] = boff + lsum[255];
}

__global__ void fill_kernel(const int* __restrict__ ei, const int* __restrict__ offsets,
                            int* __restrict__ cursor, int* __restrict__ elist) {
    int e = blockIdx.x * blockDim.x + threadIdx.x;
    if (e >= EP) return;
    int src, dst;
    if (e < EE) { src = ei[e]; dst = ei[EE + e]; } else { src = dst = e - EE; }
    int pos = atomicAdd(&cursor[dst], 1);
    elist[offsets[dst] + pos] = src;
}

// ---------------------------------------------------------------------------
// Fused gather (layers 2,3): w_e = exp(leaky_relu(s[src]+d[node])) inline;
// out[n,c] = (sum_e w_e * h[src_e,c]) / (sum_e w_e); + bias, ELU -> bf16.
// ---------------------------------------------------------------------------
template<int H, int C, int CPL>
__global__ void gather_fused(const int* __restrict__ elist,
                             const int* __restrict__ offsets,
                             const __hip_bfloat16* __restrict__ h,
                             const float* __restrict__ s, const float* __restrict__ d,
                             const float* __restrict__ b,
                             __hip_bfloat16* __restrict__ act) {
    constexpr int HC = H * C;
    constexpr int TPN = HC / CPL;
    int gid = blockIdx.x * blockDim.x + threadIdx.x;
    if (gid >= NN * TPN) return;
    int node = gid / TPN;
    int t = gid - node * TPN;
    int c0 = t * CPL;
    int hh = c0 / C;
    int j0 = offsets[node], j1 = offsets[node + 1];
    float dv = d[node * H + hh];
    float den = 0.f;
    float acc[CPL];
#pragma unroll
    for (int c = 0; c < CPL; c++) acc[c] = 0.f;
    const unsigned short* hb = (const unsigned short*)h;
    for (int j = j0; j < j1; j++) {
        int src = elist[j];
        float x = s[src * H + hh] + dv;
        x = x > 0.f ? x : 0.2f * x;
        float w = __expf(x);
        den += w;
        const unsigned short* hp = hb + (size_t)src * HC + c0;
        if constexpr (CPL == 8) {
            short8 a8 = *(const short8*)hp;
#pragma unroll
            for (int c = 0; c < 8; c++) acc[c] += w * us2f((unsigned short)a8[c]);
        } else {
            ushort2 a = *(const ushort2*)hp;
            acc[0] += w * us2f(a.x);
            acc[1] += w * us2f(a.y);
        }
    }
    float inv = 1.0f / den;   // deg >= 1 (self-loop), den > 0
    __hip_bfloat16* op = act + (size_t)node * HC + c0;
#pragma unroll
    for (int c = 0; c < CPL; c++) {
        float v = acc[c] * inv + b[c0 + c];
        v = v > 0.f ? v : (__expf(v) - 1.0f);
        op[c] = __float2bfloat16(v);
    }
}

// ---------------------------------------------------------------------------
// Final edge MLP: z[19] = [h3[src], h3[dst], ea, yr, qt] -> fc1(relu) -> fc2
// ---------------------------------------------------------------------------
__global__ void mlp_kernel(const int* __restrict__ ei,
                           const __hip_bfloat16* __restrict__ act3,
                           const float* __restrict__ ea,
                           const float* __restrict__ yr,
                           const float* __restrict__ qt,
                           const float* __restrict__ fc1w,
                           const float* __restrict__ fc1b,
                           const float* __restrict__ fc2w,
                           const float* __restrict__ fc2b,
                           float* __restrict__ outp) {
    __shared__ float w1[16 * 19], b1s[16], w2[16];
    for (int i = threadIdx.x; i < 16 * 19; i += blockDim.x) w1[i] = fc1w[i];
    if (threadIdx.x < 16) {
        b1s[threadIdx.x] = fc1b[threadIdx.x];
        w2[threadIdx.x] = fc2w[threadIdx.x];
    }
    __syncthreads();
    int e = blockIdx.x * blockDim.x + threadIdx.x;
    if (e >= EE) return;
    int src = ei[e], dst = ei[EE + e];
    short8 hs = *(const short8*)(act3 + (size_t)src * 8);
    short8 hd = *(const short8*)(act3 + (size_t)dst * 8);
    float z[19];
#pragma unroll
    for (int i = 0; i < 8; i++) z[i] = us2f((unsigned short)hs[i]);
#pragma unroll
    for (int i = 0; i < 8; i++) z[8 + i] = us2f((unsigned short)hd[i]);
    z[16] = ea[e]; z[17] = yr[e]; z[18] = qt[e];
    float acc2 = fc2b[0];
#pragma unroll
    for (int j = 0; j < 16; j++) {
        float a = b1s[j];
#pragma unroll
        for (int i = 0; i < 19; i++) a += z[i] * w1[j * 19 + i];
        a = a > 0.f ? a : 0.f;
        acc2 += a * w2[j];
    }
    outp[e] = acc2;
}

// ---------------------------------------------------------------------------
extern "C" void kernel_launch(void* const* d_in, const int* in_sizes, int n_in,
                              void* d_out, int out_size, void* d_ws, size_t ws_size,
                              hipStream_t stream) {
    const float* x    = (const float*)d_in[0];
    const int*   ei   = (const int*)d_in[1];
    const float* ea   = (const float*)d_in[2];
    const float* yr   = (const float*)d_in[3];
    const float* qt   = (const float*)d_in[4];
    const float* W1   = (const float*)d_in[5];
    const float* a1s  = (const float*)d_in[6];
    const float* a1d  = (const float*)d_in[7];
    const float* b1   = (const float*)d_in[8];
    const float* W2   = (const float*)d_in[9];
    const float* a2s  = (const float*)d_in[10];
    const float* a2d  = (const float*)d_in[11];
    const float* b2   = (const float*)d_in[12];
    const float* W3   = (const float*)d_in[13];
    const float* a3s  = (const float*)d_in[14];
    const float* a3d  = (const float*)d_in[15];
    const float* b3   = (const float*)d_in[16];
    const float* fc1w = (const float*)d_in[17];
    const float* fc1b = (const float*)d_in[18];
    const float* fc2w = (const float*)d_in[19];
    const float* fc2b = (const float*)d_in[20];
    float* outp = (float*)d_out;

    char* ws = (char*)d_ws;
    __hip_bfloat16* h_buf   = (__hip_bfloat16*)(ws);                 // N*512 bf16: pagg / h2 / h3
    __hip_bfloat16* act_buf = (__hip_bfloat16*)(ws + 51200000);      // N*512 bf16: xb / pact1 / act2 / act3
    float* s_buf   = (float*)(ws + 102400000);                       // N*4 f32
    float* d_buf   = (float*)(ws + 103200000);                       // N*4 f32
    int*   deg     = (int*)  (ws + 104000000);                       // N ints
    int*   cursor  = (int*)  (ws + 104200000);                       // N ints (contiguous w/ deg)
    int*   offsets = (int*)  (ws + 104400000);                       // N+1 ints
    int*   elist   = (int*)  (ws + 104600016);                       // EP ints (1.8 MB)
    __hip_bfloat16* pw1 = (__hip_bfloat16*)(ws + 106400016);         // 512*128 bf16 packed
    __hip_bfloat16* pw2 = (__hip_bfloat16*)(ws + 106531088);         // 128*512 bf16 packed
    float* usd  = (float*)(ws + 106662160);                          // 8*128 f32 (4 KB)
    int*   bsum = (int*)  (ws + 106666256);                          // SCB ints
    __hip_bfloat16* xb = act_buf;                                    // N*128 bf16, dead after gather_agg

    // ---- CSR build + weight pack + u-vector precompute ----
    hipMemsetAsync(deg, 0, 2 * NN * sizeof(int), stream);            // deg + cursor
    deg_kernel<<<(EP + 255) / 256, 256, 0, stream>>>(ei, deg);
    cvt2_kernel<<<(131072 + 255) / 256, 256, 0, stream>>>(W1, W2, pw1, pw2);
    usd_kernel<<<4, 256, 0, stream>>>(W1, a1s, a1d, usd);
    scan1_kernel<<<SCB, 256, 0, stream>>>(deg, bsum);
    scan2_kernel<<<SCB, 256, 0, stream>>>(deg, bsum, offsets);
    cvtx_sd<<<(NN + 63) / 64, 256, 0, stream>>>(x, usd, xb, s_buf, d_buf, NN);
    fill_kernel<<<(EP + 255) / 256, 256, 0, stream>>>(ei, offsets, cursor, elist);

    // ---- Layer 1 (restructured): gather raw x (packed out), bdiag GEMM ----
    gather_agg<<<(NN * 16 + 255) / 256, 256, 0, stream>>>(
        elist, offsets, xb, s_buf, d_buf, h_buf);
    gemm_bdiag<<<(NN + 15) / 16, 256, 0, stream>>>(h_buf, pw1, b1, act_buf, NN);

    // ---- Layer 2: 512 -> 4 heads x 32 (packed A and W) ----
    gemm_l2<<<(NN + 15) / 16, 256, 0, stream>>>(
        act_buf, pw2, a2s, a2d, h_buf, s_buf, d_buf, NN);
    gather_fused<4, 32, 2><<<(NN * 64 + 255) / 256, 256, 0, stream>>>(
        elist, offsets, h_buf, s_buf, d_buf, b2, act_buf);

    // ---- Layer 3: 128 -> 1 head x 8 ----
    gemm8_kernel<<<(NN * 8 + 255) / 256, 256, 0, stream>>>(
        act_buf, W3, a3s, a3d, h_buf, s_buf, d_buf);
    gather_fused<1, 8, 8><<<(NN + 255) / 256, 256, 0, stream>>>(
        elist, offsets, h_buf, s_buf, d_buf, b3, act_buf);

    // ---- Final edge MLP ----
    mlp_kernel<<<(EE + 255) / 256, 256, 0, stream>>>(ei, act_buf, ea, yr, qt,
                                                     fc1w, fc1b, fc2w, fc2b, outp);
}

// Round 4
// 331.804 us; speedup vs baseline: 1.6517x; 1.1024x over previous
//
#include <hip/hip_runtime.h>
#include <hip/hip_bf16.h>

#define NN 50000
#define EE 400000
#define EP 450000   // EE + NN self-loops

typedef __attribute__((ext_vector_type(8))) short short8;
typedef __attribute__((ext_vector_type(4))) float f32x4;

__device__ __forceinline__ float bf2f(__hip_bfloat16 b) { return __bfloat162float(b); }
__device__ __forceinline__ float us2f(unsigned short u) {
    unsigned int x = ((unsigned int)u) << 16;
    union { unsigned int i; float f; } c; c.i = x; return c.f;
}
__device__ __forceinline__ unsigned short f2bfu(float f) {   // f32 -> bf16 bits, RNE
    union { float f; unsigned int u; } c; c.f = f;
    unsigned int r = c.u + 0x7FFFu + ((c.u >> 16) & 1u);
    return (unsigned short)(r >> 16);
}
__device__ __forceinline__ float lrelu_exp(float x) {
    x = x > 0.f ? x : 0.2f * x;
    return __expf(x);
}

// Packed MFMA-fragment index for a [M x K] bf16 matrix consumed as A (or B with
// n in place of m) by mfma_f32_16x16x32_bf16:
//   idx(m,k) = ((m>>4)*(K/32) + (k>>5))*512 + ((k&31)>>3)*128 + (m&15)*8 + (k&7)
// A wave's fragment load is then (fragbase + lane*8): 1KB fully contiguous.

// ---------------------------------------------------------------------------
// Weight pre-convert + PACK: W1 (512x128) and W2 (128x512) f32 -> bf16 frags.
// ---------------------------------------------------------------------------
__global__ void cvt2_kernel(const float* __restrict__ W1, const float* __restrict__ W2,
                            __hip_bfloat16* __restrict__ pw1, __hip_bfloat16* __restrict__ pw2) {
    int i = blockIdx.x * blockDim.x + threadIdx.x;
    if (i < 65536) {
        int n = i >> 7, k = i & 127;   // K=128, NK=4
        int idx = ((n >> 4) * 4 + (k >> 5)) * 512 + ((k & 31) >> 3) * 128 + (n & 15) * 8 + (k & 7);
        pw1[idx] = __float2bfloat16(W1[i]);
    } else if (i < 131072) {
        int j = i - 65536;
        int n = j >> 9, k = j & 511;   // K=512, NK=16
        int idx = ((n >> 4) * 16 + (k >> 5)) * 512 + ((k & 31) >> 3) * 128 + (n & 15) * 8 + (k & 7);
        pw2[idx] = __float2bfloat16(W2[j]);
    }
}

// ---------------------------------------------------------------------------
// usd[row][k], row 0..3 = u_s per head, 4..7 = u_d per head (f32, exact):
//   u_s[h][k] = sum_c a1s[h][c] * W1[h*128+c][k]
// ---------------------------------------------------------------------------
__global__ void usd_kernel(const float* __restrict__ W1,
                           const float* __restrict__ a1s, const float* __restrict__ a1d,
                           float* __restrict__ usd) {
    int t = blockIdx.x * blockDim.x + threadIdx.x;
    if (t >= 1024) return;
    int row = t >> 7, k = t & 127;
    int hh = row & 3;
    const float* av = (row < 4) ? (a1s + hh * 128) : (a1d + hh * 128);
    const float* wp = W1 + (size_t)(hh * 128) * 128 + k;
    float acc = 0.f;
    for (int c = 0; c < 128; c++) acc += av[c] * wp[(size_t)c * 128];
    usd[t] = acc;
}

// ---------------------------------------------------------------------------
// Fused: x (f32) -> xb (bf16) convert + s1/d1 = x . usd (f32 dots, butterfly
// reduce over the 4 quads). One wave owns 16 rows, lane (r,quad) holds 32 cols.
// ---------------------------------------------------------------------------
__global__ void cvtx_sd(const float* __restrict__ x, const float* __restrict__ usd,
                        __hip_bfloat16* __restrict__ xb,
                        float* __restrict__ s, float* __restrict__ d, int M) {
    __shared__ float us_s[1024];
    for (int i = threadIdx.x; i < 1024; i += 256) us_s[i] = usd[i];
    __syncthreads();
    int wave = threadIdx.x >> 6, lane = threadIdx.x & 63;
    int m0 = blockIdx.x * 64 + wave * 16;
    int r = lane & 15, quad = lane >> 4;
    int am = m0 + r; if (am >= M) am = M - 1;
    const float* xp = x + (size_t)am * 128 + quad * 8;
    float xv[32];
#pragma unroll
    for (int kk = 0; kk < 4; kk++) {
        float4 a = *(const float4*)(xp + kk * 32);
        float4 bq = *(const float4*)(xp + kk * 32 + 4);
        xv[kk*8+0]=a.x;  xv[kk*8+1]=a.y;  xv[kk*8+2]=a.z;  xv[kk*8+3]=a.w;
        xv[kk*8+4]=bq.x; xv[kk*8+5]=bq.y; xv[kk*8+6]=bq.z; xv[kk*8+7]=bq.w;
        short8 o;
        o[0]=(short)f2bfu(a.x);  o[1]=(short)f2bfu(a.y);
        o[2]=(short)f2bfu(a.z);  o[3]=(short)f2bfu(a.w);
        o[4]=(short)f2bfu(bq.x); o[5]=(short)f2bfu(bq.y);
        o[6]=(short)f2bfu(bq.z); o[7]=(short)f2bfu(bq.w);
        *(short8*)(xb + (size_t)am * 128 + quad * 8 + kk * 32) = o;
    }
    float acc[8];
#pragma unroll
    for (int o = 0; o < 8; o++) {
        const float* up = us_s + o * 128 + quad * 8;
        float a = 0.f;
#pragma unroll
        for (int kk = 0; kk < 4; kk++)
#pragma unroll
            for (int j = 0; j < 8; j++) a += xv[kk*8+j] * up[kk*32+j];
        acc[o] = a;
    }
#pragma unroll
    for (int o = 0; o < 8; o++) {
        acc[o] += __shfl_xor(acc[o], 16, 64);
        acc[o] += __shfl_xor(acc[o], 32, 64);
    }
    int m = m0 + r;
    if (quad == 0 && m < M) {
#pragma unroll
        for (int hh = 0; hh < 4; hh++) { s[m*4+hh] = acc[hh]; d[m*4+hh] = acc[4+hh]; }
    }
}

// ---------------------------------------------------------------------------
// Layer-1 gather on RAW x. 16 lanes/node, each lane 8 x-channels, 4 head
// accumulators sharing the read. 2x edge-pipelined (independent load chains).
// Writes PACKED fragments for gemm_bdiag.
// ---------------------------------------------------------------------------
__global__ void gather_agg(const int* __restrict__ elist, const int* __restrict__ offsets,
                           const __hip_bfloat16* __restrict__ xb,
                           const float* __restrict__ s, const float* __restrict__ d,
                           __hip_bfloat16* __restrict__ pagg) {
    int gid = blockIdx.x * blockDim.x + threadIdx.x;
    if (gid >= NN * 16) return;
    int node = gid >> 4, t = gid & 15;
    int c0 = t * 8;
    int j0 = offsets[node], j1 = offsets[node + 1];
    float4 dv = *(const float4*)(d + node * 4);
    float den0=0.f, den1=0.f, den2=0.f, den3=0.f;
    float acc0[8], acc1[8], acc2[8], acc3[8];
#pragma unroll
    for (int c = 0; c < 8; c++) { acc0[c]=0.f; acc1[c]=0.f; acc2[c]=0.f; acc3[c]=0.f; }
    const unsigned short* hb = (const unsigned short*)xb;
    int j = j0;
    for (; j + 2 <= j1; j += 2) {
        int srcA = elist[j], srcB = elist[j + 1];
        float4 svA = *(const float4*)(s + srcA * 4);
        float4 svB = *(const float4*)(s + srcB * 4);
        short8 xvA = *(const short8*)(hb + (size_t)srcA * 128 + c0);
        short8 xvB = *(const short8*)(hb + (size_t)srcB * 128 + c0);
        float wA0 = lrelu_exp(svA.x + dv.x), wA1 = lrelu_exp(svA.y + dv.y);
        float wA2 = lrelu_exp(svA.z + dv.z), wA3 = lrelu_exp(svA.w + dv.w);
        float wB0 = lrelu_exp(svB.x + dv.x), wB1 = lrelu_exp(svB.y + dv.y);
        float wB2 = lrelu_exp(svB.z + dv.z), wB3 = lrelu_exp(svB.w + dv.w);
        den0 += wA0 + wB0; den1 += wA1 + wB1; den2 += wA2 + wB2; den3 += wA3 + wB3;
#pragma unroll
        for (int c = 0; c < 8; c++) {
            float xA = us2f((unsigned short)xvA[c]);
            float xB = us2f((unsigned short)xvB[c]);
            acc0[c] += wA0 * xA + wB0 * xB;
            acc1[c] += wA1 * xA + wB1 * xB;
            acc2[c] += wA2 * xA + wB2 * xB;
            acc3[c] += wA3 * xA + wB3 * xB;
        }
    }
    for (; j < j1; j++) {
        int src = elist[j];
        float4 sv = *(const float4*)(s + src * 4);
        short8 xv = *(const short8*)(hb + (size_t)src * 128 + c0);
        float w0 = lrelu_exp(sv.x + dv.x); den0 += w0;
        float w1 = lrelu_exp(sv.y + dv.y); den1 += w1;
        float w2 = lrelu_exp(sv.z + dv.z); den2 += w2;
        float w3 = lrelu_exp(sv.w + dv.w); den3 += w3;
#pragma unroll
        for (int c = 0; c < 8; c++) {
            float xf = us2f((unsigned short)xv[c]);
            acc0[c] += w0 * xf; acc1[c] += w1 * xf;
            acc2[c] += w2 * xf; acc3[c] += w3 * xf;
        }
    }
    float i0 = 1.f/den0, i1 = 1.f/den1, i2 = 1.f/den2, i3 = 1.f/den3;
    short8 o0, o1, o2, o3;
#pragma unroll
    for (int c = 0; c < 8; c++) {
        o0[c] = (short)f2bfu(acc0[c]*i0); o1[c] = (short)f2bfu(acc1[c]*i1);
        o2[c] = (short)f2bfu(acc2[c]*i2); o3[c] = (short)f2bfu(acc3[c]*i3);
    }
    // packed write: base covers tile + sub + row-in-tile; per head add frag*512
    __hip_bfloat16* base = pagg + ((size_t)(node >> 4) * 16) * 512
                         + (t & 3) * 128 + (node & 15) * 8;
    int fo = (t >> 2) * 512;
    *(short8*)(base + fo)            = o0;   // hh=0: frag hh*4+(t>>2)
    *(short8*)(base + fo + 4 * 512)  = o1;   // hh=1
    *(short8*)(base + fo + 8 * 512)  = o2;   // hh=2
    *(short8*)(base + fo + 12 * 512) = o3;   // hh=3
}

// ---------------------------------------------------------------------------
// Block-diagonal GEMM for layer-1 output, wave-per-head, packed in/out:
//   act[n, hh*128+oc] = ELU( sum_c aggn[n,hh,c] * W1[hh*128+oc, c] + b1 )
// ---------------------------------------------------------------------------
__global__ void gemm_bdiag(const __hip_bfloat16* __restrict__ pA,
                           const __hip_bfloat16* __restrict__ pW1,
                           const float* __restrict__ b,
                           __hip_bfloat16* __restrict__ pact, int M) {
    int hh = threadIdx.x >> 6, lane = threadIdx.x & 63;
    int m0 = blockIdx.x * 16;
    int r = lane & 15, quad = lane >> 4;
    short8 afrag[4];
    const __hip_bfloat16* ap = pA + ((size_t)(m0 >> 4) * 16 + hh * 4) * 512 + lane * 8;
#pragma unroll
    for (int kk = 0; kk < 4; kk++) afrag[kk] = *(const short8*)(ap + kk * 512);
#pragma unroll
    for (int nb = 0; nb < 128; nb += 16) {
        const __hip_bfloat16* bp = pW1 + ((size_t)(hh * 8 + (nb >> 4)) * 4) * 512 + lane * 8;
        f32x4 acc = {0.f, 0.f, 0.f, 0.f};
#pragma unroll
        for (int kk = 0; kk < 4; kk++) {
            short8 bfr = *(const short8*)(bp + kk * 512);
            acc = __builtin_amdgcn_mfma_f32_16x16x32_bf16(afrag[kk], bfr, acc, 0, 0, 0);
        }
        int n0 = hh * 128 + nb;
        float bias = b[n0 + r];
        // packed store: k = n0 + r, m = m0 + quad*4 + i
        int kk2 = (n0 + r) >> 5;
        int sub = ((nb & 16) + r) >> 3;
        __hip_bfloat16* op = pact + ((size_t)(m0 >> 4) * 16 + kk2) * 512
                           + sub * 128 + (r & 7);
#pragma unroll
        for (int i = 0; i < 4; i++) {
            float v = acc[i] + bias;
            v = v > 0.f ? v : (__expf(v) - 1.0f);
            op[(quad * 4 + i) * 8] = __float2bfloat16(v);
        }
    }
}

// ---------------------------------------------------------------------------
// Layer-2 GEMM, wave-per-head, packed A and W; streams af/b0/b1 per k (2 MFMA
// per A-load, ~40 VGPR). Fused s2/d2 epilogue. h2 written row-major [N][128].
// ---------------------------------------------------------------------------
__global__ void gemm_l2(const __hip_bfloat16* __restrict__ pA,
                        const __hip_bfloat16* __restrict__ pW2,
                        const float* __restrict__ as_, const float* __restrict__ ad_,
                        __hip_bfloat16* __restrict__ Cb,
                        float* __restrict__ s, float* __restrict__ d, int M) {
    int hh = threadIdx.x >> 6, lane = threadIdx.x & 63;
    int m0 = blockIdx.x * 16;
    int r = lane & 15, quad = lane >> 4;
    const __hip_bfloat16* ap  = pA + (size_t)(m0 >> 4) * 16 * 512 + lane * 8;
    const __hip_bfloat16* bp0 = pW2 + (size_t)(hh * 2) * 16 * 512 + lane * 8;
    const __hip_bfloat16* bp1 = bp0 + 16 * 512;
    f32x4 acc0 = {0.f, 0.f, 0.f, 0.f}, acc1 = {0.f, 0.f, 0.f, 0.f};
#pragma unroll
    for (int kk = 0; kk < 16; kk++) {
        short8 af = *(const short8*)(ap + kk * 512);
        short8 b0 = *(const short8*)(bp0 + kk * 512);
        short8 b1 = *(const short8*)(bp1 + kk * 512);
        acc0 = __builtin_amdgcn_mfma_f32_16x16x32_bf16(af, b0, acc0, 0, 0, 0);
        acc1 = __builtin_amdgcn_mfma_f32_16x16x32_bf16(af, b1, acc1, 0, 0, 0);
    }
    int n0 = hh * 32;
    float as0 = as_[n0 + r],      ad0 = ad_[n0 + r];
    float as1 = as_[n0 + 16 + r], ad1 = ad_[n0 + 16 + r];
    float sacc[4], dacc[4];
#pragma unroll
    for (int i = 0; i < 4; i++) {
        int m = m0 + quad * 4 + i;
        Cb[(size_t)m * 128 + n0 + r]      = __float2bfloat16(acc0[i]);
        Cb[(size_t)m * 128 + n0 + 16 + r] = __float2bfloat16(acc1[i]);
        sacc[i] = acc0[i] * as0 + acc1[i] * as1;
        dacc[i] = acc0[i] * ad0 + acc1[i] * ad1;
    }
#pragma unroll
    for (int mask = 1; mask <= 8; mask <<= 1) {
#pragma unroll
        for (int i = 0; i < 4; i++) {
            sacc[i] += __shfl_xor(sacc[i], mask, 64);
            dacc[i] += __shfl_xor(dacc[i], mask, 64);
        }
    }
    if (r == 0) {
#pragma unroll
        for (int i = 0; i < 4; i++) {
            int m = m0 + quad * 4 + i;
            s[m * 4 + hh] = sacc[i]; d[m * 4 + hh] = dacc[i];
        }
    }
}

// ---------------------------------------------------------------------------
// Tiny GEMM for layer 3 + fused s/d. Split-K: 8 lanes per node, lane t owns
// k-slice [t*16, t*16+16) for ALL 8 outputs; butterfly reduce over 8 lanes.
// ---------------------------------------------------------------------------
__global__ void gemm8_kernel(const __hip_bfloat16* __restrict__ A,
                             const float* __restrict__ W,
                             const float* __restrict__ a3s, const float* __restrict__ a3d,
                             __hip_bfloat16* __restrict__ Cb,
                             float* __restrict__ s, float* __restrict__ d) {
    int gid = blockIdx.x * blockDim.x + threadIdx.x;
    if (gid >= NN * 8) return;
    int n = gid >> 3, t = gid & 7;
    const unsigned short* ap = (const unsigned short*)A + (size_t)n * 128 + t * 16;
    short8 v0 = *(const short8*)ap;
    short8 v1 = *(const short8*)(ap + 8);
    float xf[16];
#pragma unroll
    for (int j = 0; j < 8; j++) { xf[j] = us2f((unsigned short)v0[j]); xf[8+j] = us2f((unsigned short)v1[j]); }
    float acc[8];
#pragma unroll
    for (int c = 0; c < 8; c++) {
        const float* wp = W + c * 128 + t * 16;
        float a = 0.f;
#pragma unroll
        for (int j = 0; j < 16; j++) a += xf[j] * wp[j];
        acc[c] = a;
    }
#pragma unroll
    for (int mask = 1; mask <= 4; mask <<= 1)
#pragma unroll
        for (int c = 0; c < 8; c++) acc[c] += __shfl_xor(acc[c], mask, 64);
    Cb[n * 8 + t] = __float2bfloat16(acc[t]);
    if (t == 0) {
        float sv = 0.f, dvv = 0.f;
#pragma unroll
        for (int c = 0; c < 8; c++) { sv += acc[c] * a3s[c]; dvv += acc[c] * a3d[c]; }
        s[n] = sv; d[n] = dvv;
    }
}

// ---------------------------------------------------------------------------
// CSR build: deg histogram -> two-level multi-block scan -> fill
// ---------------------------------------------------------------------------
__global__ void deg_kernel(const int* __restrict__ ei, int* __restrict__ deg) {
    int e = blockIdx.x * blockDim.x + threadIdx.x;
    if (e >= EP) return;
    int dst = (e < EE) ? ei[EE + e] : e - EE;
    atomicAdd(&deg[dst], 1);
}

#define SCB 49   // scan blocks, 1024 elements each (49*1024 = 50176 >= NN)
__global__ void scan1_kernel(const int* __restrict__ deg, int* __restrict__ bsum) {
    __shared__ int red[256];
    int b = blockIdx.x, t = threadIdx.x;
    int base = b * 1024 + t * 4;
    int s = 0;
    if (base + 3 < NN) { int4 v = *(const int4*)(deg + base); s = v.x + v.y + v.z + v.w; }
    else { for (int i = base; i < NN; i++) s += deg[i]; }
    red[t] = s;
    __syncthreads();
    for (int off = 128; off > 0; off >>= 1) {
        if (t < off) red[t] += red[t + off];
        __syncthreads();
    }
    if (t == 0) bsum[b] = red[0];
}

__global__ void scan2_kernel(const int* __restrict__ deg, const int* __restrict__ bsum,
                             int* __restrict__ offsets) {
    __shared__ int lsum[256];
    int b = blockIdx.x, t = threadIdx.x;
    int boff = 0;
    for (int i = 0; i < b; i++) boff += bsum[i];       // <=48 cached loads
    int base = b * 1024 + t * 4;
    int4 v = {0, 0, 0, 0};
    if (base + 3 < NN) v = *(const int4*)(deg + base);
    else {
        if (base < NN)     v.x = deg[base];
        if (base + 1 < NN) v.y = deg[base + 1];
        if (base + 2 < NN) v.z = deg[base + 2];
        if (base + 3 < NN) v.w = deg[base + 3];
    }
    int s = v.x + v.y + v.z + v.w;
    lsum[t] = s;
    __syncthreads();
    for (int off = 1; off < 256; off <<= 1) {
        int val = (t >= off) ? lsum[t - off] : 0;
        __syncthreads();
        lsum[t] += val;
        __syncthreads();
    }
    int ex = boff + (t ? lsum[t - 1] : 0);
    if (base < NN)     offsets[base]     = ex;
    if (base + 1 < NN) offsets[base + 1] = ex + v.x;
    if (base + 2 < NN) offsets[base + 2] = ex + v.x + v.y;
    if (base + 3 < NN) offsets[base + 3] = ex + v.x + v.y + v.z;
    if (b == SCB - 1 && t == 255) offsets[NN] = boff + lsum[255];
}

__global__ void fill_kernel(const int* __restrict__ ei, const int* __restrict__ offsets,
                            int* __restrict__ cursor, int* __restrict__ elist) {
    int e = blockIdx.x * blockDim.x + threadIdx.x;
    if (e >= EP) return;
    int src, dst;
    if (e < EE) { src = ei[e]; dst = ei[EE + e]; } else { src = dst = e - EE; }
    int pos = atomicAdd(&cursor[dst], 1);
    elist[offsets[dst] + pos] = src;
}

// ---------------------------------------------------------------------------
// Fused gather (layers 2,3): w_e = exp(leaky_relu(s[src]+d[node])) inline;
// out[n,c] = (sum_e w_e * h[src_e,c]) / (sum_e w_e); + bias, ELU -> bf16.
// 4x edge-pipelined: 4 independent elist->s/h load chains in flight.
// For TPN==64 (wave == node) the CSR bounds are made wave-uniform so the
// elist loads become scalar (constant-cache) loads.
// ---------------------------------------------------------------------------
template<int H, int C, int CPL>
__global__ void gather_fused(const int* __restrict__ elist,
                             const int* __restrict__ offsets,
                             const __hip_bfloat16* __restrict__ h,
                             const float* __restrict__ s, const float* __restrict__ d,
                             const float* __restrict__ b,
                             __hip_bfloat16* __restrict__ act) {
    constexpr int HC = H * C;
    constexpr int TPN = HC / CPL;
    int gid = blockIdx.x * blockDim.x + threadIdx.x;
    if (gid >= NN * TPN) return;
    int node = gid / TPN;
    int t = gid - node * TPN;
    int c0 = t * CPL;
    int hh = c0 / C;
    int j0 = offsets[node], j1 = offsets[node + 1];
    if constexpr (TPN == 64) {   // wave == node exactly (NN*64 threads)
        j0 = __builtin_amdgcn_readfirstlane(j0);
        j1 = __builtin_amdgcn_readfirstlane(j1);
    }
    float dv = d[node * H + hh];
    float den = 0.f;
    float acc[CPL];
#pragma unroll
    for (int c = 0; c < CPL; c++) acc[c] = 0.f;
    const unsigned short* hb = (const unsigned short*)h;
    int j = j0;
    for (; j + 4 <= j1; j += 4) {
        int sA = elist[j], sB = elist[j + 1], sC = elist[j + 2], sD = elist[j + 3];
        float eA = s[sA * H + hh] + dv;
        float eB = s[sB * H + hh] + dv;
        float eC = s[sC * H + hh] + dv;
        float eD = s[sD * H + hh] + dv;
        const unsigned short* pA = hb + (size_t)sA * HC + c0;
        const unsigned short* pB = hb + (size_t)sB * HC + c0;
        const unsigned short* pC = hb + (size_t)sC * HC + c0;
        const unsigned short* pD = hb + (size_t)sD * HC + c0;
        if constexpr (CPL == 8) {
            short8 vA = *(const short8*)pA;
            short8 vB = *(const short8*)pB;
            short8 vC = *(const short8*)pC;
            short8 vD = *(const short8*)pD;
            float wA = lrelu_exp(eA), wB = lrelu_exp(eB);
            float wC = lrelu_exp(eC), wD = lrelu_exp(eD);
            den += (wA + wB) + (wC + wD);
#pragma unroll
            for (int c = 0; c < 8; c++) {
                acc[c] += wA * us2f((unsigned short)vA[c]) + wB * us2f((unsigned short)vB[c])
                        + wC * us2f((unsigned short)vC[c]) + wD * us2f((unsigned short)vD[c]);
            }
        } else {
            ushort2 vA = *(const ushort2*)pA;
            ushort2 vB = *(const ushort2*)pB;
            ushort2 vC = *(const ushort2*)pC;
            ushort2 vD = *(const ushort2*)pD;
            float wA = lrelu_exp(eA), wB = lrelu_exp(eB);
            float wC = lrelu_exp(eC), wD = lrelu_exp(eD);
            den += (wA + wB) + (wC + wD);
            acc[0] += wA * us2f(vA.x) + wB * us2f(vB.x) + wC * us2f(vC.x) + wD * us2f(vD.x);
            acc[1] += wA * us2f(vA.y) + wB * us2f(vB.y) + wC * us2f(vC.y) + wD * us2f(vD.y);
        }
    }
    for (; j < j1; j++) {
        int src = elist[j];
        float w = lrelu_exp(s[src * H + hh] + dv);
        den += w;
        const unsigned short* hp = hb + (size_t)src * HC + c0;
        if constexpr (CPL == 8) {
            short8 a8 = *(const short8*)hp;
#pragma unroll
            for (int c = 0; c < 8; c++) acc[c] += w * us2f((unsigned short)a8[c]);
        } else {
            ushort2 a = *(const ushort2*)hp;
            acc[0] += w * us2f(a.x);
            acc[1] += w * us2f(a.y);
        }
    }
    float inv = 1.0f / den;   // deg >= 1 (self-loop), den > 0
    __hip_bfloat16* op = act + (size_t)node * HC + c0;
#pragma unroll
    for (int c = 0; c < CPL; c++) {
        float v = acc[c] * inv + b[c0 + c];
        v = v > 0.f ? v : (__expf(v) - 1.0f);
        op[c] = __float2bfloat16(v);
    }
}

// ---------------------------------------------------------------------------
// Final edge MLP: z[19] = [h3[src], h3[dst], ea, yr, qt] -> fc1(relu) -> fc2
// ---------------------------------------------------------------------------
__global__ void mlp_kernel(const int* __restrict__ ei,
                           const __hip_bfloat16* __restrict__ act3,
                           const float* __restrict__ ea,
                           const float* __restrict__ yr,
                           const float* __restrict__ qt,
                           const float* __restrict__ fc1w,
                           const float* __restrict__ fc1b,
                           const float* __restrict__ fc2w,
                           const float* __restrict__ fc2b,
                           float* __restrict__ outp) {
    __shared__ float w1[16 * 19], b1s[16], w2[16];
    for (int i = threadIdx.x; i < 16 * 19; i += blockDim.x) w1[i] = fc1w[i];
    if (threadIdx.x < 16) {
        b1s[threadIdx.x] = fc1b[threadIdx.x];
        w2[threadIdx.x] = fc2w[threadIdx.x];
    }
    __syncthreads();
    int e = blockIdx.x * blockDim.x + threadIdx.x;
    if (e >= EE) return;
    int src = ei[e], dst = ei[EE + e];
    short8 hs = *(const short8*)(act3 + (size_t)src * 8);
    short8 hd = *(const short8*)(act3 + (size_t)dst * 8);
    float z[19];
#pragma unroll
    for (int i = 0; i < 8; i++) z[i] = us2f((unsigned short)hs[i]);
#pragma unroll
    for (int i = 0; i < 8; i++) z[8 + i] = us2f((unsigned short)hd[i]);
    z[16] = ea[e]; z[17] = yr[e]; z[18] = qt[e];
    float acc2 = fc2b[0];
#pragma unroll
    for (int j = 0; j < 16; j++) {
        float a = b1s[j];
#pragma unroll
        for (int i = 0; i < 19; i++) a += z[i] * w1[j * 19 + i];
        a = a > 0.f ? a : 0.f;
        acc2 += a * w2[j];
    }
    outp[e] = acc2;
}

// ---------------------------------------------------------------------------
extern "C" void kernel_launch(void* const* d_in, const int* in_sizes, int n_in,
                              void* d_out, int out_size, void* d_ws, size_t ws_size,
                              hipStream_t stream) {
    const float* x    = (const float*)d_in[0];
    const int*   ei   = (const int*)d_in[1];
    const float* ea   = (const float*)d_in[2];
    const float* yr   = (const float*)d_in[3];
    const float* qt   = (const float*)d_in[4];
    const float* W1   = (const float*)d_in[5];
    const float* a1s  = (const float*)d_in[6];
    const float* a1d  = (const float*)d_in[7];
    const float* b1   = (const float*)d_in[8];
    const float* W2   = (const float*)d_in[9];
    const float* a2s  = (const float*)d_in[10];
    const float* a2d  = (const float*)d_in[11];
    const float* b2   = (const float*)d_in[12];
    const float* W3   = (const float*)d_in[13];
    const float* a3s  = (const float*)d_in[14];
    const float* a3d  = (const float*)d_in[15];
    const float* b3   = (const float*)d_in[16];
    const float* fc1w = (const float*)d_in[17];
    const float* fc1b = (const float*)d_in[18];
    const float* fc2w = (const float*)d_in[19];
    const float* fc2b = (const float*)d_in[20];
    float* outp = (float*)d_out;

    char* ws = (char*)d_ws;
    __hip_bfloat16* h_buf   = (__hip_bfloat16*)(ws);                 // N*512 bf16: pagg / h2 / h3
    __hip_bfloat16* act_buf = (__hip_bfloat16*)(ws + 51200000);      // N*512 bf16: xb / pact1 / act2 / act3
    float* s_buf   = (float*)(ws + 102400000);                       // N*4 f32
    float* d_buf   = (float*)(ws + 103200000);                       // N*4 f32
    int*   deg     = (int*)  (ws + 104000000);                       // N ints
    int*   cursor  = (int*)  (ws + 104200000);                       // N ints (contiguous w/ deg)
    int*   offsets = (int*)  (ws + 104400000);                       // N+1 ints
    int*   elist   = (int*)  (ws + 104600016);                       // EP ints (1.8 MB)
    __hip_bfloat16* pw1 = (__hip_bfloat16*)(ws + 106400016);         // 512*128 bf16 packed
    __hip_bfloat16* pw2 = (__hip_bfloat16*)(ws + 106531088);         // 128*512 bf16 packed
    float* usd  = (float*)(ws + 106662160);                          // 8*128 f32 (4 KB)
    int*   bsum = (int*)  (ws + 106666256);                          // SCB ints
    __hip_bfloat16* xb = act_buf;                                    // N*128 bf16, dead after gather_agg

    // ---- CSR build + weight pack + u-vector precompute ----
    hipMemsetAsync(deg, 0, 2 * NN * sizeof(int), stream);            // deg + cursor
    deg_kernel<<<(EP + 255) / 256, 256, 0, stream>>>(ei, deg);
    cvt2_kernel<<<(131072 + 255) / 256, 256, 0, stream>>>(W1, W2, pw1, pw2);
    usd_kernel<<<4, 256, 0, stream>>>(W1, a1s, a1d, usd);
    scan1_kernel<<<SCB, 256, 0, stream>>>(deg, bsum);
    scan2_kernel<<<SCB, 256, 0, stream>>>(deg, bsum, offsets);
    cvtx_sd<<<(NN + 63) / 64, 256, 0, stream>>>(x, usd, xb, s_buf, d_buf, NN);
    fill_kernel<<<(EP + 255) / 256, 256, 0, stream>>>(ei, offsets, cursor, elist);

    // ---- Layer 1 (restructured): gather raw x (packed out), bdiag GEMM ----
    gather_agg<<<(NN * 16 + 255) / 256, 256, 0, stream>>>(
        elist, offsets, xb, s_buf, d_buf, h_buf);
    gemm_bdiag<<<(NN + 15) / 16, 256, 0, stream>>>(h_buf, pw1, b1, act_buf, NN);

    // ---- Layer 2: 512 -> 4 heads x 32 (packed A and W) ----
    gemm_l2<<<(NN + 15) / 16, 256, 0, stream>>>(
        act_buf, pw2, a2s, a2d, h_buf, s_buf, d_buf, NN);
    gather_fused<4, 32, 2><<<(NN * 64 + 255) / 256, 256, 0, stream>>>(
        elist, offsets, h_buf, s_buf, d_buf, b2, act_buf);

    // ---- Layer 3: 128 -> 1 head x 8 ----
    gemm8_kernel<<<(NN * 8 + 255) / 256, 256, 0, stream>>>(
        act_buf, W3, a3s, a3d, h_buf, s_buf, d_buf);
    gather_fused<1, 8, 8><<<(NN + 255) / 256, 256, 0, stream>>>(
        elist, offsets, h_buf, s_buf, d_buf, b3, act_buf);

    // ---- Final edge MLP ----
    mlp_kernel<<<(EE + 255) / 256, 256, 0, stream>>>(ei, act_buf, ea, yr, qt,
                                                     fc1w, fc1b, fc2w, fc2b, outp);
}